// Round 4
// baseline (534.637 us; speedup 1.0000x reference)
//
#include <hip/hip_runtime.h>
#include <hip/hip_bf16.h>

#define N_NODES 50000
#define N_EDGES 800000
#define MP 50048  // N_NODES padded to multiple of 64

typedef unsigned short ushort_t;
typedef unsigned int uint_t;
typedef __attribute__((ext_vector_type(8))) __bf16 bf16x8;
typedef __attribute__((ext_vector_type(4))) float f32x4;
typedef __attribute__((ext_vector_type(4))) uint_t u32x4;

__device__ __forceinline__ float bf2f(uint_t u) {
    union { uint_t i; float f; } v; v.i = u << 16; return v.f;
}
__device__ __forceinline__ ushort_t f2bf(float f) {
    union { float f; uint_t i; } v; v.f = f;
    uint_t u = v.i;
    return (ushort_t)((u + 0x7FFFu + ((u >> 16) & 1u)) >> 16);
}
__device__ __forceinline__ void acc8v(float* a, u32x4 d) {
    #pragma unroll
    for (int p = 0; p < 4; ++p) {
        a[2 * p]     += bf2f(d[p] & 0xffff);
        a[2 * p + 1] += bf2f(d[p] >> 16);
    }
}

// ---------------- CSR build ----------------
__global__ void deg_k(const int* __restrict__ dst, int* __restrict__ deg, int E) {
    int e = blockIdx.x * 256 + threadIdx.x;
    if (e < E) atomicAdd(&deg[dst[e]], 1);
}

__global__ void scan1_k(const int* __restrict__ deg, int* __restrict__ offs,
                        int* __restrict__ bsum, int n) {
    __shared__ int s[256];
    int i = blockIdx.x * 256 + threadIdx.x;
    int v = (i < n) ? deg[i] : 0;
    s[threadIdx.x] = v;
    __syncthreads();
    #pragma unroll
    for (int d = 1; d < 256; d <<= 1) {
        int t = (threadIdx.x >= d) ? s[threadIdx.x - d] : 0;
        __syncthreads();
        s[threadIdx.x] += t;
        __syncthreads();
    }
    if (i < n) offs[i] = s[threadIdx.x] - v;   // exclusive
    if (threadIdx.x == 255) bsum[blockIdx.x] = s[255];
}

__global__ void scan2_k(int* __restrict__ bsum, int nb) {  // single block
    __shared__ int s[256];
    int v = (threadIdx.x < nb) ? bsum[threadIdx.x] : 0;
    s[threadIdx.x] = v;
    __syncthreads();
    #pragma unroll
    for (int d = 1; d < 256; d <<= 1) {
        int t = (threadIdx.x >= d) ? s[threadIdx.x - d] : 0;
        __syncthreads();
        s[threadIdx.x] += t;
        __syncthreads();
    }
    if (threadIdx.x < nb) bsum[threadIdx.x] = s[threadIdx.x] - v;  // exclusive
}

__global__ void scan3_k(int* __restrict__ offs, const int* __restrict__ bsum, int n, int E) {
    int i = blockIdx.x * 256 + threadIdx.x;
    if (i < n) offs[i] += bsum[blockIdx.x];
    if (i == 0) offs[n] = E;
}

__global__ void scat_k(const int* __restrict__ src, const int* __restrict__ dst,
                       int* __restrict__ cur, int* __restrict__ csrc, int E) {
    int e = blockIdx.x * 256 + threadIdx.x;
    if (e < E) {
        int p = atomicAdd(&cur[dst[e]], 1);
        csrc[p] = src[e];
    }
}

// ---------------- f32 -> bf16 convert ----------------
__global__ void cvt_k(const float* __restrict__ x, ushort_t* __restrict__ o, long long n) {
    long long i = ((long long)blockIdx.x * 256 + threadIdx.x) * 4;
    if (i >= n) return;
    float4 v = *reinterpret_cast<const float4*>(x + i);
    uint2 w;
    w.x = (uint_t)f2bf(v.x) | ((uint_t)f2bf(v.y) << 16);
    w.y = (uint_t)f2bf(v.z) | ((uint_t)f2bf(v.w) << 16);
    *reinterpret_cast<uint2*>(o + i) = w;
}

// ---------------- weight-pair packing into MFMA B-fragment order ----------------
// packs [Wl | Wr] (each [K,F]) as one [K, 2F] matrix in frag order.
// frag (kt, ct): value(lane, j) = W[kt*32 + (lane>>4)*8 + j][ct*16 + (lane&15)]
__global__ void pack2_k(const float* __restrict__ Wl, const float* __restrict__ Wr,
                        ushort_t* __restrict__ P, int K, int F) {
    int NOUT = 2 * F;
    int tid = blockIdx.x * 256 + threadIdx.x;
    int total = (K / 32) * (NOUT / 16) * 64;
    if (tid >= total) return;
    int lane = tid & 63;
    int frag = tid >> 6;
    int nct = NOUT / 16;
    int ct = frag % nct;
    int kt = frag / nct;
    int col = ct * 16 + (lane & 15);
    const float* W = (col < F) ? Wl : Wr;
    int c = (col < F) ? col : col - F;
    int k0 = kt * 32 + (lane >> 4) * 8;
    uint_t w[4];
    #pragma unroll
    for (int p = 0; p < 4; ++p) {
        ushort_t lo = f2bf(W[(long long)(k0 + 2 * p) * F + c]);
        ushort_t hi = f2bf(W[(long long)(k0 + 2 * p + 1) * F + c]);
        w[p] = (uint_t)lo | ((uint_t)hi << 16);
    }
    *(reinterpret_cast<uint4*>(P) + tid) = make_uint4(w[0], w[1], w[2], w[3]);
}

// ---------------- GEMM: C[MP,NOUT] = A[MP,K] @ Bp (frag-packed) ----------------
template <int K, int NOUT>
__global__ __launch_bounds__(256) void gemm_k(
    const ushort_t* __restrict__ A, const ushort_t* __restrict__ Bp,
    ushort_t* __restrict__ C) {
    constexpr int KT = K / 32;
    constexpr int CTW = NOUT / 64;
    int wave = threadIdx.x >> 6;
    int lane = threadIdx.x & 63;
    int rowBase = blockIdx.x * 64;
    int arowoff = lane & 15;
    int kgrp = (lane >> 4) * 8;
    int ct0 = wave * CTW;

    f32x4 acc[4][CTW];
    #pragma unroll
    for (int r = 0; r < 4; ++r)
        #pragma unroll
        for (int c = 0; c < CTW; ++c) acc[r][c] = (f32x4){0.f, 0.f, 0.f, 0.f};

    const ushort_t* Ab = A + (long long)rowBase * K + kgrp;
    #pragma unroll
    for (int kt = 0; kt < KT; ++kt) {
        bf16x8 a[4];
        #pragma unroll
        for (int r = 0; r < 4; ++r)
            a[r] = *reinterpret_cast<const bf16x8*>(
                Ab + (long long)(r * 16 + arowoff) * K + kt * 32);
        #pragma unroll
        for (int ct = 0; ct < CTW; ++ct) {
            bf16x8 b = *reinterpret_cast<const bf16x8*>(
                Bp + ((long long)(kt * (NOUT / 16) + ct0 + ct) * 64 + lane) * 8);
            #pragma unroll
            for (int r = 0; r < 4; ++r)
                acc[r][ct] = __builtin_amdgcn_mfma_f32_16x16x32_bf16(a[r], b, acc[r][ct], 0, 0, 0);
        }
    }

    int colb = lane & 15;
    int r0 = (lane >> 4) * 4;
    #pragma unroll
    for (int r = 0; r < 4; ++r) {
        #pragma unroll
        for (int ct = 0; ct < CTW; ++ct) {
            int col = (ct0 + ct) * 16 + colb;
            #pragma unroll
            for (int j = 0; j < 4; ++j) {
                int row = rowBase + r * 16 + r0 + j;
                C[(long long)row * NOUT + col] = f2bf(acc[r][ct][j]);
            }
        }
    }
}

// ---------------- fused aggregate + epilogue, XCD column-sliced ----------------
// C = [P | R] rows of width 2F (bf16). out = act(segmean_gather(P) + R + bias).
// slice = blockIdx.x % NS selects a 32-col (64B) slice; with round-robin
// blockIdx->XCD dispatch, each XCD's gather footprint is 50000*64B = 3.2MB
// -> fits the 4MB per-XCD L2, so the ~16 touches/row become L2 hits.
// One node per wave; 4-lane groups x 16B = one 64B line per edge; 16 edges
// in flight. Gather loads cached; R/csrc nontemporal (streamed once).
template <int F, bool RELU, bool F32OUT>
__global__ __launch_bounds__(256) void agg_k(
    const ushort_t* __restrict__ C, const int* __restrict__ offs,
    const int* __restrict__ csrc, const float* __restrict__ bias,
    ushort_t* __restrict__ H, float* __restrict__ hout, int n) {
    constexpr int NS = F / 32;   // slices per row: 8, 4, 2
    constexpr int S = 2 * F;     // C row stride (elems)
    int slice = blockIdx.x % NS;
    int node = (blockIdx.x / NS) * 4 + (threadIdx.x >> 6);
    if (node >= n) return;
    int lane = threadIdx.x & 63;
    int sub = lane & 3;          // 4 subs x 8 cols = 32-col slice
    int g = lane >> 2;           // 16 edge-groups
    int colbase = slice * 32 + sub * 8;
    int beg = offs[node], end = offs[node + 1];

    float a[8] = {0.f, 0.f, 0.f, 0.f, 0.f, 0.f, 0.f, 0.f};
    const ushort_t* Cs = C + colbase;

    int e = beg;
    while (e + 16 <= end) {
        int s = __builtin_nontemporal_load(csrc + e + g);
        u32x4 d = *reinterpret_cast<const u32x4*>(Cs + (size_t)s * S);
        acc8v(a, d);
        e += 16;
    }
    if (e + g < end) {
        int s = __builtin_nontemporal_load(csrc + e + g);
        u32x4 d = *reinterpret_cast<const u32x4*>(Cs + (size_t)s * S);
        acc8v(a, d);
    }

    // reduce across the 16 edge-groups (bits 2..5 of lane)
    #pragma unroll
    for (int off = 4; off < 64; off <<= 1) {
        #pragma unroll
        for (int i = 0; i < 8; ++i) a[i] += __shfl_xor(a[i], off);
    }

    if (lane < 4) {
        float inv = 1.f / fmaxf((float)(end - beg), 1.f);
        u32x4 rr = __builtin_nontemporal_load(
            reinterpret_cast<const u32x4*>(C + (size_t)node * S + F + colbase));
        float4 bA = *reinterpret_cast<const float4*>(bias + colbase);
        float4 bB = *reinterpret_cast<const float4*>(bias + colbase + 4);
        float bv[8] = {bA.x, bA.y, bA.z, bA.w, bB.x, bB.y, bB.z, bB.w};
        float v[8];
        #pragma unroll
        for (int p = 0; p < 4; ++p) {
            v[2 * p]     = a[2 * p] * inv + bf2f(rr[p] & 0xffff) + bv[2 * p];
            v[2 * p + 1] = a[2 * p + 1] * inv + bf2f(rr[p] >> 16) + bv[2 * p + 1];
        }
        if (RELU) {
            #pragma unroll
            for (int i = 0; i < 8; ++i) v[i] = fmaxf(v[i], 0.f);
        }
        if (F32OUT) {
            f32x4 w0 = {v[0], v[1], v[2], v[3]};
            f32x4 w1 = {v[4], v[5], v[6], v[7]};
            float* o = hout + (size_t)node * F + colbase;
            *reinterpret_cast<f32x4*>(o) = w0;
            *reinterpret_cast<f32x4*>(o + 4) = w1;
        } else {
            u32x4 w;
            #pragma unroll
            for (int p = 0; p < 4; ++p)
                w[p] = (uint_t)f2bf(v[2 * p]) | ((uint_t)f2bf(v[2 * p + 1]) << 16);
            __builtin_nontemporal_store(
                w, reinterpret_cast<u32x4*>(H + (size_t)node * F + colbase));
        }
    }
}

// ---------------- log_softmax over rows of 64 (one wave per row) ----------------
__global__ void lsm_k(const float* __restrict__ h, float* __restrict__ o, int M) {
    int wid = (blockIdx.x * 256 + threadIdx.x) >> 6;
    if (wid >= M) return;
    int lane = threadIdx.x & 63;
    float v = h[(long long)wid * 64 + lane];
    float m = v;
    #pragma unroll
    for (int d = 32; d >= 1; d >>= 1) m = fmaxf(m, __shfl_xor(m, d));
    float e = expf(v - m);
    float s = e;
    #pragma unroll
    for (int d = 32; d >= 1; d >>= 1) s += __shfl_xor(s, d);
    o[(long long)wid * 64 + lane] = v - m - logf(s);
}

extern "C" void kernel_launch(void* const* d_in, const int* in_sizes, int n_in,
                              void* d_out, int out_size, void* d_ws, size_t ws_size,
                              hipStream_t stream) {
    const float* x   = (const float*)d_in[0];
    const int*   ei  = (const int*)d_in[1];
    const float* W1l = (const float*)d_in[2];
    const float* b1  = (const float*)d_in[3];
    const float* W1r = (const float*)d_in[4];
    const float* W2l = (const float*)d_in[5];
    const float* b2  = (const float*)d_in[6];
    const float* W2r = (const float*)d_in[7];
    const float* W3l = (const float*)d_in[8];
    const float* b3  = (const float*)d_in[9];
    const float* W3r = (const float*)d_in[10];
    const int* esrc = ei;
    const int* edst = ei + N_EDGES;

    char* ws = (char*)d_ws;
    size_t off = 0;
    auto alloc = [&](size_t b) { void* p = ws + off; off = (off + b + 255) & ~(size_t)255; return p; };
    ushort_t* bufA = (ushort_t*)alloc((size_t)MP * 256 * 2);
    ushort_t* bufB = (ushort_t*)alloc((size_t)MP * 512 * 2);
    ushort_t* bufC = (ushort_t*)alloc((size_t)MP * 256 * 2);
    int* offs = (int*)alloc((N_NODES + 1) * 4);
    int* cur  = (int*)alloc(N_NODES * 4);
    int* csrc = (int*)alloc(N_EDGES * 4);
    int* bsum = (int*)alloc(256 * 4);
    ushort_t* pB1 = (ushort_t*)alloc(256 * 512 * 2);
    ushort_t* pB2 = (ushort_t*)alloc(256 * 256 * 2);
    ushort_t* pB3 = (ushort_t*)alloc(128 * 128 * 2);

    ushort_t* Xbf = bufA;
    ushort_t* C1  = bufB;
    ushort_t* H1  = bufC;
    ushort_t* C2  = bufA;
    ushort_t* H2  = bufB;
    ushort_t* C3  = bufC;

    int nScanBlocks = (N_NODES + 255) / 256;  // 196

    // CSR build (reused by all 3 layers)
    hipMemsetAsync(cur, 0, N_NODES * 4, stream);
    deg_k<<<(N_EDGES + 255) / 256, 256, 0, stream>>>(edst, cur, N_EDGES);
    scan1_k<<<nScanBlocks, 256, 0, stream>>>(cur, offs, bsum, N_NODES);
    scan2_k<<<1, 256, 0, stream>>>(bsum, nScanBlocks);
    scan3_k<<<nScanBlocks, 256, 0, stream>>>(offs, bsum, N_NODES, N_EDGES);
    hipMemcpyAsync(cur, offs, N_NODES * 4, hipMemcpyDeviceToDevice, stream);
    scat_k<<<(N_EDGES + 255) / 256, 256, 0, stream>>>(esrc, edst, cur, csrc, N_EDGES);

    // x -> bf16
    cvt_k<<<(int)(((long long)N_NODES * 256 / 4 + 255) / 256), 256, 0, stream>>>(
        x, Xbf, (long long)N_NODES * 256);

    // pack weight pairs [Wl|Wr]
    pack2_k<<<(16384 + 255) / 256, 256, 0, stream>>>(W1l, W1r, pB1, 256, 256);
    pack2_k<<<(8192 + 255) / 256, 256, 0, stream>>>(W2l, W2r, pB2, 256, 128);
    pack2_k<<<(2048 + 255) / 256, 256, 0, stream>>>(W3l, W3r, pB3, 128, 64);

    int gemmGrid = MP / 64;                    // 782
    int nodeBlocks = (N_NODES + 3) / 4;        // 12500
    float* hout = (float*)d_out;
    float* lout = hout + (long long)N_NODES * 64;

    // layer 1
    gemm_k<256, 512><<<gemmGrid, 256, 0, stream>>>(Xbf, pB1, C1);
    agg_k<256, true, false><<<8 * nodeBlocks, 256, 0, stream>>>(
        C1, offs, csrc, b1, H1, nullptr, N_NODES);
    // layer 2
    gemm_k<256, 256><<<gemmGrid, 256, 0, stream>>>(H1, pB2, C2);
    agg_k<128, true, false><<<4 * nodeBlocks, 256, 0, stream>>>(
        C2, offs, csrc, b2, H2, nullptr, N_NODES);
    // layer 3 (f32 h out), then log_softmax
    gemm_k<128, 128><<<gemmGrid, 256, 0, stream>>>(H2, pB3, C3);
    agg_k<64, false, true><<<2 * nodeBlocks, 256, 0, stream>>>(
        C3, offs, csrc, b3, nullptr, hout, N_NODES);
    lsm_k<<<(N_NODES * 64 + 255) / 256, 256, 0, stream>>>(hout, lout, N_NODES);
}

// Round 5
// 317.661 us; speedup vs baseline: 1.6830x; 1.6830x over previous
//
#include <hip/hip_runtime.h>
#include <hip/hip_bf16.h>

#define N_NODES 50000
#define N_EDGES 800000
#define MP 50048  // N_NODES padded to multiple of 64

typedef unsigned short ushort_t;
typedef unsigned int uint_t;
typedef __attribute__((ext_vector_type(8))) __bf16 bf16x8;
typedef __attribute__((ext_vector_type(4))) float f32x4;
typedef __attribute__((ext_vector_type(2))) float f32x2;

__device__ __forceinline__ float bf2f(uint_t u) {
    union { uint_t i; float f; } v; v.i = u << 16; return v.f;
}
__device__ __forceinline__ ushort_t f2bf(float f) {
    union { float f; uint_t i; } v; v.f = f;
    uint_t u = v.i;
    return (ushort_t)((u + 0x7FFFu + ((u >> 16) & 1u)) >> 16);
}
__device__ __forceinline__ void acc4(float* a, uint2 d) {
    a[0] += bf2f(d.x & 0xffff); a[1] += bf2f(d.x >> 16);
    a[2] += bf2f(d.y & 0xffff); a[3] += bf2f(d.y >> 16);
}
// accumulate 8 fp8 (e4m3) values held in a uint2
__device__ __forceinline__ void accf8(float* a, uint2 d) {
    f32x2 p;
    p = __builtin_amdgcn_cvt_pk_f32_fp8(d.x, false); a[0] += p.x; a[1] += p.y;
    p = __builtin_amdgcn_cvt_pk_f32_fp8(d.x, true);  a[2] += p.x; a[3] += p.y;
    p = __builtin_amdgcn_cvt_pk_f32_fp8(d.y, false); a[4] += p.x; a[5] += p.y;
    p = __builtin_amdgcn_cvt_pk_f32_fp8(d.y, true);  a[6] += p.x; a[7] += p.y;
}

// ---------------- CSR build ----------------
__global__ void deg_k(const int* __restrict__ dst, int* __restrict__ deg, int E) {
    int e = blockIdx.x * 256 + threadIdx.x;
    if (e < E) atomicAdd(&deg[dst[e]], 1);
}

__global__ void scan1_k(const int* __restrict__ deg, int* __restrict__ offs,
                        int* __restrict__ bsum, int n) {
    __shared__ int s[256];
    int i = blockIdx.x * 256 + threadIdx.x;
    int v = (i < n) ? deg[i] : 0;
    s[threadIdx.x] = v;
    __syncthreads();
    #pragma unroll
    for (int d = 1; d < 256; d <<= 1) {
        int t = (threadIdx.x >= d) ? s[threadIdx.x - d] : 0;
        __syncthreads();
        s[threadIdx.x] += t;
        __syncthreads();
    }
    if (i < n) offs[i] = s[threadIdx.x] - v;   // exclusive
    if (threadIdx.x == 255) bsum[blockIdx.x] = s[255];
}

__global__ void scan2_k(int* __restrict__ bsum, int nb) {  // single block
    __shared__ int s[256];
    int v = (threadIdx.x < nb) ? bsum[threadIdx.x] : 0;
    s[threadIdx.x] = v;
    __syncthreads();
    #pragma unroll
    for (int d = 1; d < 256; d <<= 1) {
        int t = (threadIdx.x >= d) ? s[threadIdx.x - d] : 0;
        __syncthreads();
        s[threadIdx.x] += t;
        __syncthreads();
    }
    if (threadIdx.x < nb) bsum[threadIdx.x] = s[threadIdx.x] - v;  // exclusive
}

__global__ void scan3_k(int* __restrict__ offs, const int* __restrict__ bsum, int n, int E) {
    int i = blockIdx.x * 256 + threadIdx.x;
    if (i < n) offs[i] += bsum[blockIdx.x];
    if (i == 0) offs[n] = E;
}

__global__ void scat_k(const int* __restrict__ src, const int* __restrict__ dst,
                       int* __restrict__ cur, int* __restrict__ csrc, int E) {
    int e = blockIdx.x * 256 + threadIdx.x;
    if (e < E) {
        int p = atomicAdd(&cur[dst[e]], 1);
        csrc[p] = src[e];
    }
}

// ---------------- f32 -> bf16 convert ----------------
__global__ void cvt_k(const float* __restrict__ x, ushort_t* __restrict__ o, long long n) {
    long long i = ((long long)blockIdx.x * 256 + threadIdx.x) * 4;
    if (i >= n) return;
    float4 v = *reinterpret_cast<const float4*>(x + i);
    uint2 w;
    w.x = (uint_t)f2bf(v.x) | ((uint_t)f2bf(v.y) << 16);
    w.y = (uint_t)f2bf(v.z) | ((uint_t)f2bf(v.w) << 16);
    *reinterpret_cast<uint2*>(o + i) = w;
}

// ---------------- weight-pair packing into MFMA B-fragment order ----------------
// packs [Wl | Wr] (each [K,F]) as one [K, 2F] matrix in frag order.
// frag (kt, ct): value(lane, j) = W[kt*32 + (lane>>4)*8 + j][ct*16 + (lane&15)]
__global__ void pack2_k(const float* __restrict__ Wl, const float* __restrict__ Wr,
                        ushort_t* __restrict__ P, int K, int F) {
    int NOUT = 2 * F;
    int tid = blockIdx.x * 256 + threadIdx.x;
    int total = (K / 32) * (NOUT / 16) * 64;
    if (tid >= total) return;
    int lane = tid & 63;
    int frag = tid >> 6;
    int nct = NOUT / 16;
    int ct = frag % nct;
    int kt = frag / nct;
    int col = ct * 16 + (lane & 15);
    const float* W = (col < F) ? Wl : Wr;
    int c = (col < F) ? col : col - F;
    int k0 = kt * 32 + (lane >> 4) * 8;
    uint_t w[4];
    #pragma unroll
    for (int p = 0; p < 4; ++p) {
        ushort_t lo = f2bf(W[(long long)(k0 + 2 * p) * F + c]);
        ushort_t hi = f2bf(W[(long long)(k0 + 2 * p + 1) * F + c]);
        w[p] = (uint_t)lo | ((uint_t)hi << 16);
    }
    *(reinterpret_cast<uint4*>(P) + tid) = make_uint4(w[0], w[1], w[2], w[3]);
}

// ---------------- GEMM: [P|R] = A[MP,K] @ Bp (frag-packed) ----------------
// cols < PF  -> fp8 e4m3 to Pout (row stride PF)
// cols >= PF -> bf16 to Rout (row stride NOUT-PF)
template <int K, int NOUT, int PF>
__global__ __launch_bounds__(256) void gemm_k(
    const ushort_t* __restrict__ A, const ushort_t* __restrict__ Bp,
    unsigned char* __restrict__ Pout, ushort_t* __restrict__ Rout) {
    constexpr int KT = K / 32;
    constexpr int CTW = NOUT / 64;
    constexpr int RS = NOUT - PF;   // R row stride
    int wave = threadIdx.x >> 6;
    int lane = threadIdx.x & 63;
    int rowBase = blockIdx.x * 64;
    int arowoff = lane & 15;
    int kgrp = (lane >> 4) * 8;
    int ct0 = wave * CTW;

    f32x4 acc[4][CTW];
    #pragma unroll
    for (int r = 0; r < 4; ++r)
        #pragma unroll
        for (int c = 0; c < CTW; ++c) acc[r][c] = (f32x4){0.f, 0.f, 0.f, 0.f};

    const ushort_t* Ab = A + (long long)rowBase * K + kgrp;
    #pragma unroll
    for (int kt = 0; kt < KT; ++kt) {
        bf16x8 a[4];
        #pragma unroll
        for (int r = 0; r < 4; ++r)
            a[r] = *reinterpret_cast<const bf16x8*>(
                Ab + (long long)(r * 16 + arowoff) * K + kt * 32);
        #pragma unroll
        for (int ct = 0; ct < CTW; ++ct) {
            bf16x8 b = *reinterpret_cast<const bf16x8*>(
                Bp + ((long long)(kt * (NOUT / 16) + ct0 + ct) * 64 + lane) * 8);
            #pragma unroll
            for (int r = 0; r < 4; ++r)
                acc[r][ct] = __builtin_amdgcn_mfma_f32_16x16x32_bf16(a[r], b, acc[r][ct], 0, 0, 0);
        }
    }

    int colb = lane & 15;
    int r0 = (lane >> 4) * 4;
    #pragma unroll
    for (int r = 0; r < 4; ++r) {
        #pragma unroll
        for (int ct = 0; ct < CTW; ++ct) {
            int col = (ct0 + ct) * 16 + colb;
            #pragma unroll
            for (int j = 0; j < 4; ++j) {
                int row = rowBase + r * 16 + r0 + j;
                float v = acc[r][ct][j];
                if (PF > 0 && col < PF) {
                    uint_t b8 = __builtin_amdgcn_cvt_pk_fp8_f32(v, v, 0u, false);
                    Pout[(size_t)row * PF + col] = (unsigned char)(b8 & 0xff);
                } else {
                    Rout[(size_t)row * RS + (col - PF)] = f2bf(v);
                }
            }
        }
    }
}

// ---------------- fused aggregate (fp8 P) + epilogue, 2 nodes/wave ----------------
// h = relu(segmean_gather(P_fp8) + R_bf16 + bias) -> H bf16.
// LPG lanes x 8B cover one fp8 row; G=64/LPG edge groups; U edges per group
// per iter; 4 edges/node/iter x 2 nodes = 8 gathers in flight.
template <int F>
__global__ __launch_bounds__(256) void aggP8_k(
    const unsigned char* __restrict__ P, const int* __restrict__ offs,
    const int* __restrict__ csrc, const ushort_t* __restrict__ R,
    const float* __restrict__ bias, ushort_t* __restrict__ H, int n) {
    constexpr int LPG = F / 8;     // 32 (F=256), 16 (F=128)
    constexpr int G = 64 / LPG;    // 2, 4
    constexpr int U = 4 / G;       // 2, 1
    int wid = (blockIdx.x * 256 + threadIdx.x) >> 6;
    int lane = threadIdx.x & 63;
    int g = lane / LPG;
    int sub = lane & (LPG - 1);
    int colbase = sub * 8;
    int n0 = 2 * wid, n1 = 2 * wid + 1;
    if (n0 >= n) return;
    bool has1 = (n1 < n);
    int b0 = offs[n0], end0 = offs[n0 + 1];
    int b1 = has1 ? offs[n1] : 0, end1 = has1 ? offs[n1 + 1] : 0;

    float a0[8] = {0,0,0,0,0,0,0,0};
    float a1[8] = {0,0,0,0,0,0,0,0};
    int e0 = b0, e1 = b1;
    const unsigned char* Pc = P + colbase;

    while (e0 + 4 <= end0 && e1 + 4 <= end1) {
        uint2 d0[U], d1[U];
        #pragma unroll
        for (int u = 0; u < U; ++u) {
            int s = csrc[e0 + g + u * G];
            d0[u] = *reinterpret_cast<const uint2*>(Pc + (size_t)s * F);
        }
        #pragma unroll
        for (int u = 0; u < U; ++u) {
            int s = csrc[e1 + g + u * G];
            d1[u] = *reinterpret_cast<const uint2*>(Pc + (size_t)s * F);
        }
        #pragma unroll
        for (int u = 0; u < U; ++u) { accf8(a0, d0[u]); accf8(a1, d1[u]); }
        e0 += 4; e1 += 4;
    }
    while (e0 + 4 <= end0) {
        uint2 d[U];
        #pragma unroll
        for (int u = 0; u < U; ++u) {
            int s = csrc[e0 + g + u * G];
            d[u] = *reinterpret_cast<const uint2*>(Pc + (size_t)s * F);
        }
        #pragma unroll
        for (int u = 0; u < U; ++u) accf8(a0, d[u]);
        e0 += 4;
    }
    for (int e = e0 + g; e < end0; e += G) {
        int s = csrc[e];
        uint2 d = *reinterpret_cast<const uint2*>(Pc + (size_t)s * F);
        accf8(a0, d);
    }
    while (e1 + 4 <= end1) {
        uint2 d[U];
        #pragma unroll
        for (int u = 0; u < U; ++u) {
            int s = csrc[e1 + g + u * G];
            d[u] = *reinterpret_cast<const uint2*>(Pc + (size_t)s * F);
        }
        #pragma unroll
        for (int u = 0; u < U; ++u) accf8(a1, d[u]);
        e1 += 4;
    }
    for (int e = e1 + g; e < end1; e += G) {
        int s = csrc[e];
        uint2 d = *reinterpret_cast<const uint2*>(Pc + (size_t)s * F);
        accf8(a1, d);
    }

    // combine the G edge-groups
    #pragma unroll
    for (int off = LPG; off < 64; off <<= 1) {
        #pragma unroll
        for (int i = 0; i < 8; ++i) {
            a0[i] += __shfl_xor(a0[i], off);
            a1[i] += __shfl_xor(a1[i], off);
        }
    }

    if (lane < LPG) {
        float inv0 = 1.f / fmaxf((float)(end0 - b0), 1.f);
        float inv1 = 1.f / fmaxf((float)(end1 - b1), 1.f);
        #pragma unroll
        for (int j = 0; j < 2; ++j) {
            if (j && !has1) break;
            int node = j ? n1 : n0;
            float* a = j ? a1 : a0;
            float inv = j ? inv1 : inv0;
            uint4 rr = *reinterpret_cast<const uint4*>(R + (size_t)node * F + colbase);
            float r[8];
            r[0] = bf2f(rr.x & 0xffff); r[1] = bf2f(rr.x >> 16);
            r[2] = bf2f(rr.y & 0xffff); r[3] = bf2f(rr.y >> 16);
            r[4] = bf2f(rr.z & 0xffff); r[5] = bf2f(rr.z >> 16);
            r[6] = bf2f(rr.w & 0xffff); r[7] = bf2f(rr.w >> 16);
            float4 bA = *reinterpret_cast<const float4*>(bias + colbase);
            float4 bB = *reinterpret_cast<const float4*>(bias + colbase + 4);
            float bv[8] = {bA.x, bA.y, bA.z, bA.w, bB.x, bB.y, bB.z, bB.w};
            uint_t w[4];
            #pragma unroll
            for (int p = 0; p < 4; ++p) {
                float v0 = fmaxf(a[2 * p] * inv + r[2 * p] + bv[2 * p], 0.f);
                float v1 = fmaxf(a[2 * p + 1] * inv + r[2 * p + 1] + bv[2 * p + 1], 0.f);
                w[p] = (uint_t)f2bf(v0) | ((uint_t)f2bf(v1) << 16);
            }
            *reinterpret_cast<uint4*>(H + (size_t)node * F + colbase) =
                make_uint4(w[0], w[1], w[2], w[3]);
        }
    }
}

// ---------------- final layer: aggregate (bf16 C=[P|R], F=64) + log_softmax ----------------
__global__ __launch_bounds__(256) void aggF_k(
    const ushort_t* __restrict__ C, const int* __restrict__ offs,
    const int* __restrict__ csrc, const float* __restrict__ bias,
    float* __restrict__ hout, float* __restrict__ lout, int n) {
    constexpr int F = 64;
    constexpr int LPG = 16;        // 16 lanes x 4 cols = 64 cols
    constexpr int G = 4;
    constexpr int S = 128;
    int wid = (blockIdx.x * 256 + threadIdx.x) >> 6;
    int lane = threadIdx.x & 63;
    int g = lane >> 4;
    int sub = lane & 15;
    int colbase = sub * 4;
    int n0 = 2 * wid, n1 = 2 * wid + 1;
    if (n0 >= n) return;
    bool has1 = (n1 < n);
    int b0 = offs[n0], end0 = offs[n0 + 1];
    int b1 = has1 ? offs[n1] : 0, end1 = has1 ? offs[n1 + 1] : 0;

    float a0[4] = {0, 0, 0, 0};
    float a1[4] = {0, 0, 0, 0};
    int e0 = b0, e1 = b1;

    while (e0 + 4 <= end0 && e1 + 4 <= end1) {
        int s0 = csrc[e0 + g], s1 = csrc[e1 + g];
        uint2 d0 = *reinterpret_cast<const uint2*>(C + (size_t)s0 * S + colbase);
        uint2 d1 = *reinterpret_cast<const uint2*>(C + (size_t)s1 * S + colbase);
        acc4(a0, d0); acc4(a1, d1);
        e0 += 4; e1 += 4;
    }
    while (e0 + 4 <= end0) {
        int s = csrc[e0 + g];
        uint2 d = *reinterpret_cast<const uint2*>(C + (size_t)s * S + colbase);
        acc4(a0, d);
        e0 += 4;
    }
    for (int e = e0 + g; e < end0; e += G) {
        int s = csrc[e];
        uint2 d = *reinterpret_cast<const uint2*>(C + (size_t)s * S + colbase);
        acc4(a0, d);
    }
    while (e1 + 4 <= end1) {
        int s = csrc[e1 + g];
        uint2 d = *reinterpret_cast<const uint2*>(C + (size_t)s * S + colbase);
        acc4(a1, d);
        e1 += 4;
    }
    for (int e = e1 + g; e < end1; e += G) {
        int s = csrc[e];
        uint2 d = *reinterpret_cast<const uint2*>(C + (size_t)s * S + colbase);
        acc4(a1, d);
    }

    #pragma unroll
    for (int off = LPG; off < 64; off <<= 1) {
        #pragma unroll
        for (int i = 0; i < 4; ++i) {
            a0[i] += __shfl_xor(a0[i], off);
            a1[i] += __shfl_xor(a1[i], off);
        }
    }

    float inv0 = 1.f / fmaxf((float)(end0 - b0), 1.f);
    float inv1 = 1.f / fmaxf((float)(end1 - b1), 1.f);

    #pragma unroll
    for (int j = 0; j < 2; ++j) {
        if (j && !has1) break;
        int node = j ? n1 : n0;
        float* a = j ? a1 : a0;
        float inv = j ? inv1 : inv0;
        uint2 rr = *reinterpret_cast<const uint2*>(C + (size_t)node * S + F + colbase);
        float4 bv = *reinterpret_cast<const float4*>(bias + colbase);
        float v0 = a[0] * inv + bf2f(rr.x & 0xffff) + bv.x;
        float v1 = a[1] * inv + bf2f(rr.x >> 16) + bv.y;
        float v2 = a[2] * inv + bf2f(rr.y & 0xffff) + bv.z;
        float v3 = a[3] * inv + bf2f(rr.y >> 16) + bv.w;
        float m = fmaxf(fmaxf(v0, v1), fmaxf(v2, v3));
        #pragma unroll
        for (int off = 1; off < LPG; off <<= 1) m = fmaxf(m, __shfl_xor(m, off));
        float s = expf(v0 - m) + expf(v1 - m) + expf(v2 - m) + expf(v3 - m);
        #pragma unroll
        for (int off = 1; off < LPG; off <<= 1) s += __shfl_xor(s, off);
        float ls = logf(s);
        if (lane < LPG) {
            *reinterpret_cast<float4*>(hout + (size_t)node * 64 + colbase) =
                make_float4(v0, v1, v2, v3);
            *reinterpret_cast<float4*>(lout + (size_t)node * 64 + colbase) =
                make_float4(v0 - m - ls, v1 - m - ls, v2 - m - ls, v3 - m - ls);
        }
    }
}

extern "C" void kernel_launch(void* const* d_in, const int* in_sizes, int n_in,
                              void* d_out, int out_size, void* d_ws, size_t ws_size,
                              hipStream_t stream) {
    const float* x   = (const float*)d_in[0];
    const int*   ei  = (const int*)d_in[1];
    const float* W1l = (const float*)d_in[2];
    const float* b1  = (const float*)d_in[3];
    const float* W1r = (const float*)d_in[4];
    const float* W2l = (const float*)d_in[5];
    const float* b2  = (const float*)d_in[6];
    const float* W2r = (const float*)d_in[7];
    const float* W3l = (const float*)d_in[8];
    const float* b3  = (const float*)d_in[9];
    const float* W3r = (const float*)d_in[10];
    const int* esrc = ei;
    const int* edst = ei + N_EDGES;

    char* ws = (char*)d_ws;
    size_t off = 0;
    auto alloc = [&](size_t b) { void* p = ws + off; off = (off + b + 255) & ~(size_t)255; return p; };
    ushort_t* Xbf = (ushort_t*)alloc((size_t)MP * 256 * 2);       // later: C3 (bf16 [P3|R3], width 128)
    unsigned char* P1 = (unsigned char*)alloc((size_t)MP * 256);  // fp8; later: P2 (width 128 fp8)
    ushort_t* R1 = (ushort_t*)alloc((size_t)MP * 256 * 2);        // bf16; later: R2 (width 128)
    ushort_t* H1 = (ushort_t*)alloc((size_t)MP * 256 * 2);
    ushort_t* H2 = (ushort_t*)alloc((size_t)MP * 128 * 2);
    int* offs = (int*)alloc((N_NODES + 1) * 4);
    int* cur  = (int*)alloc(N_NODES * 4);
    int* csrc = (int*)alloc(N_EDGES * 4);
    int* bsum = (int*)alloc(256 * 4);
    ushort_t* pB1 = (ushort_t*)alloc(256 * 512 * 2);
    ushort_t* pB2 = (ushort_t*)alloc(256 * 256 * 2);
    ushort_t* pB3 = (ushort_t*)alloc(128 * 128 * 2);

    unsigned char* P2 = P1;           // alias (P1 dead after agg1)
    ushort_t* R2 = R1;                // alias (R1 dead after agg1)
    ushort_t* C3 = Xbf;               // alias (Xbf dead after gemm1)

    int nScanBlocks = (N_NODES + 255) / 256;  // 196

    // CSR build (reused by all 3 layers)
    hipMemsetAsync(cur, 0, N_NODES * 4, stream);
    deg_k<<<(N_EDGES + 255) / 256, 256, 0, stream>>>(edst, cur, N_EDGES);
    scan1_k<<<nScanBlocks, 256, 0, stream>>>(cur, offs, bsum, N_NODES);
    scan2_k<<<1, 256, 0, stream>>>(bsum, nScanBlocks);
    scan3_k<<<nScanBlocks, 256, 0, stream>>>(offs, bsum, N_NODES, N_EDGES);
    hipMemcpyAsync(cur, offs, N_NODES * 4, hipMemcpyDeviceToDevice, stream);
    scat_k<<<(N_EDGES + 255) / 256, 256, 0, stream>>>(esrc, edst, cur, csrc, N_EDGES);

    // x -> bf16
    cvt_k<<<(int)(((long long)N_NODES * 256 / 4 + 255) / 256), 256, 0, stream>>>(
        x, Xbf, (long long)N_NODES * 256);

    // pack weight pairs [Wl|Wr]
    pack2_k<<<(16384 + 255) / 256, 256, 0, stream>>>(W1l, W1r, pB1, 256, 256);
    pack2_k<<<(8192 + 255) / 256, 256, 0, stream>>>(W2l, W2r, pB2, 256, 128);
    pack2_k<<<(2048 + 255) / 256, 256, 0, stream>>>(W3l, W3r, pB3, 128, 64);

    int gemmGrid = MP / 64;                    // 782
    int aggGrid = ((N_NODES + 1) / 2 + 3) / 4; // 6250 blocks (2 nodes/wave, 4 waves)
    float* hout = (float*)d_out;
    float* lout = hout + (long long)N_NODES * 64;

    // layer 1: P1(fp8) | R1(bf16) = Xbf @ [W1l|W1r]; h1 = relu(mean(P1) + R1 + b1)
    gemm_k<256, 512, 256><<<gemmGrid, 256, 0, stream>>>(Xbf, pB1, P1, R1);
    aggP8_k<256><<<aggGrid, 256, 0, stream>>>(P1, offs, csrc, R1, b1, H1, N_NODES);
    // layer 2
    gemm_k<256, 256, 128><<<gemmGrid, 256, 0, stream>>>(H1, pB2, P2, R2);
    aggP8_k<128><<<aggGrid, 256, 0, stream>>>(P2, offs, csrc, R2, b2, H2, N_NODES);
    // layer 3: C3 = [P3|R3] bf16; fused mean + bias + log_softmax
    gemm_k<128, 128, 0><<<gemmGrid, 256, 0, stream>>>(H2, pB3, nullptr, C3);
    aggF_k<<<aggGrid, 256, 0, stream>>>(C3, offs, csrc, b3, hout, lout, N_NODES);
}

// Round 6
// 308.676 us; speedup vs baseline: 1.7320x; 1.0291x over previous
//
#include <hip/hip_runtime.h>
#include <hip/hip_bf16.h>

#define N_NODES 50000
#define N_EDGES 800000
#define MP 50048  // N_NODES padded to multiple of 64

typedef unsigned short ushort_t;
typedef unsigned int uint_t;
typedef __attribute__((ext_vector_type(8))) __bf16 bf16x8;
typedef __attribute__((ext_vector_type(4))) float f32x4;
typedef __attribute__((ext_vector_type(2))) float f32x2;

__device__ __forceinline__ float bf2f(uint_t u) {
    union { uint_t i; float f; } v; v.i = u << 16; return v.f;
}
__device__ __forceinline__ ushort_t f2bf(float f) {
    union { float f; uint_t i; } v; v.f = f;
    uint_t u = v.i;
    return (ushort_t)((u + 0x7FFFu + ((u >> 16) & 1u)) >> 16);
}
__device__ __forceinline__ void acc4(float* a, uint2 d) {
    a[0] += bf2f(d.x & 0xffff); a[1] += bf2f(d.x >> 16);
    a[2] += bf2f(d.y & 0xffff); a[3] += bf2f(d.y >> 16);
}
// accumulate 8 fp8 (e4m3) values held in a uint2
__device__ __forceinline__ void accf8(float* a, uint2 d) {
    f32x2 p;
    p = __builtin_amdgcn_cvt_pk_f32_fp8(d.x, false); a[0] += p.x; a[1] += p.y;
    p = __builtin_amdgcn_cvt_pk_f32_fp8(d.x, true);  a[2] += p.x; a[3] += p.y;
    p = __builtin_amdgcn_cvt_pk_f32_fp8(d.y, false); a[4] += p.x; a[5] += p.y;
    p = __builtin_amdgcn_cvt_pk_f32_fp8(d.y, true);  a[6] += p.x; a[7] += p.y;
}

// ---------------- CSR build ----------------
__global__ void deg_k(const int* __restrict__ dst, int* __restrict__ deg, int E) {
    int e = blockIdx.x * 256 + threadIdx.x;
    if (e < E) atomicAdd(&deg[dst[e]], 1);
}

__global__ void scan1_k(const int* __restrict__ deg, int* __restrict__ offs,
                        int* __restrict__ bsum, int n) {
    __shared__ int s[256];
    int i = blockIdx.x * 256 + threadIdx.x;
    int v = (i < n) ? deg[i] : 0;
    s[threadIdx.x] = v;
    __syncthreads();
    #pragma unroll
    for (int d = 1; d < 256; d <<= 1) {
        int t = (threadIdx.x >= d) ? s[threadIdx.x - d] : 0;
        __syncthreads();
        s[threadIdx.x] += t;
        __syncthreads();
    }
    if (i < n) offs[i] = s[threadIdx.x] - v;   // exclusive
    if (threadIdx.x == 255) bsum[blockIdx.x] = s[255];
}

__global__ void scan2_k(int* __restrict__ bsum, int nb) {  // single block
    __shared__ int s[256];
    int v = (threadIdx.x < nb) ? bsum[threadIdx.x] : 0;
    s[threadIdx.x] = v;
    __syncthreads();
    #pragma unroll
    for (int d = 1; d < 256; d <<= 1) {
        int t = (threadIdx.x >= d) ? s[threadIdx.x - d] : 0;
        __syncthreads();
        s[threadIdx.x] += t;
        __syncthreads();
    }
    if (threadIdx.x < nb) bsum[threadIdx.x] = s[threadIdx.x] - v;  // exclusive
}

__global__ void scan3_k(int* __restrict__ offs, const int* __restrict__ bsum, int n, int E) {
    int i = blockIdx.x * 256 + threadIdx.x;
    if (i < n) offs[i] += bsum[blockIdx.x];
    if (i == 0) offs[n] = E;
}

__global__ void scat_k(const int* __restrict__ src, const int* __restrict__ dst,
                       int* __restrict__ cur, int* __restrict__ csrc, int E) {
    int e = blockIdx.x * 256 + threadIdx.x;
    if (e < E) {
        int p = atomicAdd(&cur[dst[e]], 1);
        csrc[p] = src[e];
    }
}

// ---------------- f32 -> bf16 convert ----------------
__global__ void cvt_k(const float* __restrict__ x, ushort_t* __restrict__ o, long long n) {
    long long i = ((long long)blockIdx.x * 256 + threadIdx.x) * 4;
    if (i >= n) return;
    float4 v = *reinterpret_cast<const float4*>(x + i);
    uint2 w;
    w.x = (uint_t)f2bf(v.x) | ((uint_t)f2bf(v.y) << 16);
    w.y = (uint_t)f2bf(v.z) | ((uint_t)f2bf(v.w) << 16);
    *reinterpret_cast<uint2*>(o + i) = w;
}

// ---------------- weight-pair packing into MFMA fragment order ----------------
// packs [Wl | Wr] (each [K,F]) as one [K, 2F] matrix in frag order.
// frag (kt, ct): value(lane, j) = W[kt*32 + (lane>>4)*8 + j][ct*16 + (lane&15)]
__global__ void pack2_k(const float* __restrict__ Wl, const float* __restrict__ Wr,
                        ushort_t* __restrict__ P, int K, int F) {
    int NOUT = 2 * F;
    int tid = blockIdx.x * 256 + threadIdx.x;
    int total = (K / 32) * (NOUT / 16) * 64;
    if (tid >= total) return;
    int lane = tid & 63;
    int frag = tid >> 6;
    int nct = NOUT / 16;
    int ct = frag % nct;
    int kt = frag / nct;
    int col = ct * 16 + (lane & 15);
    const float* W = (col < F) ? Wl : Wr;
    int c = (col < F) ? col : col - F;
    int k0 = kt * 32 + (lane >> 4) * 8;
    uint_t w[4];
    #pragma unroll
    for (int p = 0; p < 4; ++p) {
        ushort_t lo = f2bf(W[(long long)(k0 + 2 * p) * F + c]);
        ushort_t hi = f2bf(W[(long long)(k0 + 2 * p + 1) * F + c]);
        w[p] = (uint_t)lo | ((uint_t)hi << 16);
    }
    *(reinterpret_cast<uint4*>(P) + tid) = make_uint4(w[0], w[1], w[2], w[3]);
}

// ---------------- GEMM (operand-swapped): [P|R] = A[MP,K] @ Bp ----------------
// Weight frag fed as MFMA A-operand, x frag as B-operand -> D[wcol][xrow]:
// thread holds 4 CONSECUTIVE output cols (wc..wc+3) of one row -> packed stores.
// cols < PF -> fp8 e4m3 u32 store; cols >= PF -> bf16 uint2 store.
template <int K, int NOUT, int PF>
__global__ __launch_bounds__(256) void gemm_k(
    const ushort_t* __restrict__ A, const ushort_t* __restrict__ Bp,
    unsigned char* __restrict__ Pout, ushort_t* __restrict__ Rout) {
    constexpr int KT = K / 32;
    constexpr int CTW = NOUT / 64;   // col-tiles per wave
    constexpr int RS = NOUT - PF;    // R row stride
    constexpr int RB = 2;            // 32 rows per block
    int wave = threadIdx.x >> 6;
    int lane = threadIdx.x & 63;
    int rowBase = blockIdx.x * (16 * RB);
    int arowoff = lane & 15;
    int kgrp = (lane >> 4) * 8;
    int ct0 = wave * CTW;

    f32x4 acc[RB][CTW];
    #pragma unroll
    for (int r = 0; r < RB; ++r)
        #pragma unroll
        for (int c = 0; c < CTW; ++c) acc[r][c] = (f32x4){0.f, 0.f, 0.f, 0.f};

    const ushort_t* Ab = A + (long long)rowBase * K + kgrp;
    #pragma unroll
    for (int kt = 0; kt < KT; ++kt) {
        bf16x8 xf[RB];
        #pragma unroll
        for (int r = 0; r < RB; ++r)
            xf[r] = *reinterpret_cast<const bf16x8*>(
                Ab + (long long)(r * 16 + arowoff) * K + kt * 32);
        #pragma unroll
        for (int ct = 0; ct < CTW; ++ct) {
            bf16x8 wf = *reinterpret_cast<const bf16x8*>(
                Bp + ((long long)(kt * (NOUT / 16) + ct0 + ct) * 64 + lane) * 8);
            #pragma unroll
            for (int r = 0; r < RB; ++r)
                acc[r][ct] = __builtin_amdgcn_mfma_f32_16x16x32_bf16(wf, xf[r], acc[r][ct], 0, 0, 0);
        }
    }

    int r0 = (lane >> 4) * 4;   // wcol sub-offset
    #pragma unroll
    for (int r = 0; r < RB; ++r) {
        int xrow = rowBase + r * 16 + arowoff;
        #pragma unroll
        for (int ct = 0; ct < CTW; ++ct) {
            int wc = (ct0 + ct) * 16 + r0;
            f32x4 v = acc[r][ct];
            if (PF > 0 && wc < PF) {
                uint_t u = __builtin_amdgcn_cvt_pk_fp8_f32(v[0], v[1], 0u, false);
                u = __builtin_amdgcn_cvt_pk_fp8_f32(v[2], v[3], u, true);
                *reinterpret_cast<uint_t*>(Pout + (size_t)xrow * PF + wc) = u;
            } else {
                uint2 w;
                w.x = (uint_t)f2bf(v[0]) | ((uint_t)f2bf(v[1]) << 16);
                w.y = (uint_t)f2bf(v[2]) | ((uint_t)f2bf(v[3]) << 16);
                *reinterpret_cast<uint2*>(Rout + (size_t)xrow * RS + (wc - PF)) = w;
            }
        }
    }
}

// ---------------- fused aggregate (fp8 P) + epilogue, 2 nodes/wave ----------------
// h = relu(segmean_gather(P_fp8) + R_bf16 + bias) -> H bf16.
template <int F>
__global__ __launch_bounds__(256) void aggP8_k(
    const unsigned char* __restrict__ P, const int* __restrict__ offs,
    const int* __restrict__ csrc, const ushort_t* __restrict__ R,
    const float* __restrict__ bias, ushort_t* __restrict__ H, int n) {
    constexpr int LPG = F / 8;     // 32 (F=256), 16 (F=128)
    constexpr int G = 64 / LPG;    // 2, 4
    constexpr int U = 4 / G;       // 2, 1
    int wid = (blockIdx.x * 256 + threadIdx.x) >> 6;
    int lane = threadIdx.x & 63;
    int g = lane / LPG;
    int sub = lane & (LPG - 1);
    int colbase = sub * 8;
    int n0 = 2 * wid, n1 = 2 * wid + 1;
    if (n0 >= n) return;
    bool has1 = (n1 < n);
    int b0 = offs[n0], end0 = offs[n0 + 1];
    int b1 = has1 ? offs[n1] : 0, end1 = has1 ? offs[n1 + 1] : 0;

    float a0[8] = {0,0,0,0,0,0,0,0};
    float a1[8] = {0,0,0,0,0,0,0,0};
    int e0 = b0, e1 = b1;
    const unsigned char* Pc = P + colbase;

    while (e0 + 4 <= end0 && e1 + 4 <= end1) {
        uint2 d0[U], d1[U];
        #pragma unroll
        for (int u = 0; u < U; ++u) {
            int s = csrc[e0 + g + u * G];
            d0[u] = *reinterpret_cast<const uint2*>(Pc + (size_t)s * F);
        }
        #pragma unroll
        for (int u = 0; u < U; ++u) {
            int s = csrc[e1 + g + u * G];
            d1[u] = *reinterpret_cast<const uint2*>(Pc + (size_t)s * F);
        }
        #pragma unroll
        for (int u = 0; u < U; ++u) { accf8(a0, d0[u]); accf8(a1, d1[u]); }
        e0 += 4; e1 += 4;
    }
    while (e0 + 4 <= end0) {
        uint2 d[U];
        #pragma unroll
        for (int u = 0; u < U; ++u) {
            int s = csrc[e0 + g + u * G];
            d[u] = *reinterpret_cast<const uint2*>(Pc + (size_t)s * F);
        }
        #pragma unroll
        for (int u = 0; u < U; ++u) accf8(a0, d[u]);
        e0 += 4;
    }
    for (int e = e0 + g; e < end0; e += G) {
        int s = csrc[e];
        uint2 d = *reinterpret_cast<const uint2*>(Pc + (size_t)s * F);
        accf8(a0, d);
    }
    while (e1 + 4 <= end1) {
        uint2 d[U];
        #pragma unroll
        for (int u = 0; u < U; ++u) {
            int s = csrc[e1 + g + u * G];
            d[u] = *reinterpret_cast<const uint2*>(Pc + (size_t)s * F);
        }
        #pragma unroll
        for (int u = 0; u < U; ++u) accf8(a1, d[u]);
        e1 += 4;
    }
    for (int e = e1 + g; e < end1; e += G) {
        int s = csrc[e];
        uint2 d = *reinterpret_cast<const uint2*>(Pc + (size_t)s * F);
        accf8(a1, d);
    }

    // combine the G edge-groups
    #pragma unroll
    for (int off = LPG; off < 64; off <<= 1) {
        #pragma unroll
        for (int i = 0; i < 8; ++i) {
            a0[i] += __shfl_xor(a0[i], off);
            a1[i] += __shfl_xor(a1[i], off);
        }
    }

    if (lane < LPG) {
        float inv0 = 1.f / fmaxf((float)(end0 - b0), 1.f);
        float inv1 = 1.f / fmaxf((float)(end1 - b1), 1.f);
        #pragma unroll
        for (int j = 0; j < 2; ++j) {
            if (j && !has1) break;
            int node = j ? n1 : n0;
            float* a = j ? a1 : a0;
            float inv = j ? inv1 : inv0;
            uint4 rr = *reinterpret_cast<const uint4*>(R + (size_t)node * F + colbase);
            float r[8];
            r[0] = bf2f(rr.x & 0xffff); r[1] = bf2f(rr.x >> 16);
            r[2] = bf2f(rr.y & 0xffff); r[3] = bf2f(rr.y >> 16);
            r[4] = bf2f(rr.z & 0xffff); r[5] = bf2f(rr.z >> 16);
            r[6] = bf2f(rr.w & 0xffff); r[7] = bf2f(rr.w >> 16);
            float4 bA = *reinterpret_cast<const float4*>(bias + colbase);
            float4 bB = *reinterpret_cast<const float4*>(bias + colbase + 4);
            float bv[8] = {bA.x, bA.y, bA.z, bA.w, bB.x, bB.y, bB.z, bB.w};
            uint_t w[4];
            #pragma unroll
            for (int p = 0; p < 4; ++p) {
                float v0 = fmaxf(a[2 * p] * inv + r[2 * p] + bv[2 * p], 0.f);
                float v1 = fmaxf(a[2 * p + 1] * inv + r[2 * p + 1] + bv[2 * p + 1], 0.f);
                w[p] = (uint_t)f2bf(v0) | ((uint_t)f2bf(v1) << 16);
            }
            *reinterpret_cast<uint4*>(H + (size_t)node * F + colbase) =
                make_uint4(w[0], w[1], w[2], w[3]);
        }
    }
}

// ---------------- final layer: aggregate (bf16 C=[P|R], F=64) + log_softmax ----------------
__global__ __launch_bounds__(256) void aggF_k(
    const ushort_t* __restrict__ C, const int* __restrict__ offs,
    const int* __restrict__ csrc, const float* __restrict__ bias,
    float* __restrict__ hout, float* __restrict__ lout, int n) {
    constexpr int F = 64;
    constexpr int LPG = 16;        // 16 lanes x 4 cols = 64 cols
    constexpr int G = 4;
    constexpr int S = 128;
    int wid = (blockIdx.x * 256 + threadIdx.x) >> 6;
    int lane = threadIdx.x & 63;
    int g = lane >> 4;
    int sub = lane & 15;
    int colbase = sub * 4;
    int n0 = 2 * wid, n1 = 2 * wid + 1;
    if (n0 >= n) return;
    bool has1 = (n1 < n);
    int b0 = offs[n0], end0 = offs[n0 + 1];
    int b1 = has1 ? offs[n1] : 0, end1 = has1 ? offs[n1 + 1] : 0;

    float a0[4] = {0, 0, 0, 0};
    float a1[4] = {0, 0, 0, 0};
    int e0 = b0, e1 = b1;

    while (e0 + 4 <= end0 && e1 + 4 <= end1) {
        int s0 = csrc[e0 + g], s1 = csrc[e1 + g];
        uint2 d0 = *reinterpret_cast<const uint2*>(C + (size_t)s0 * S + colbase);
        uint2 d1 = *reinterpret_cast<const uint2*>(C + (size_t)s1 * S + colbase);
        acc4(a0, d0); acc4(a1, d1);
        e0 += 4; e1 += 4;
    }
    while (e0 + 4 <= end0) {
        int s = csrc[e0 + g];
        uint2 d = *reinterpret_cast<const uint2*>(C + (size_t)s * S + colbase);
        acc4(a0, d);
        e0 += 4;
    }
    for (int e = e0 + g; e < end0; e += G) {
        int s = csrc[e];
        uint2 d = *reinterpret_cast<const uint2*>(C + (size_t)s * S + colbase);
        acc4(a0, d);
    }
    while (e1 + 4 <= end1) {
        int s = csrc[e1 + g];
        uint2 d = *reinterpret_cast<const uint2*>(C + (size_t)s * S + colbase);
        acc4(a1, d);
        e1 += 4;
    }
    for (int e = e1 + g; e < end1; e += G) {
        int s = csrc[e];
        uint2 d = *reinterpret_cast<const uint2*>(C + (size_t)s * S + colbase);
        acc4(a1, d);
    }

    #pragma unroll
    for (int off = LPG; off < 64; off <<= 1) {
        #pragma unroll
        for (int i = 0; i < 4; ++i) {
            a0[i] += __shfl_xor(a0[i], off);
            a1[i] += __shfl_xor(a1[i], off);
        }
    }

    float inv0 = 1.f / fmaxf((float)(end0 - b0), 1.f);
    float inv1 = 1.f / fmaxf((float)(end1 - b1), 1.f);

    #pragma unroll
    for (int j = 0; j < 2; ++j) {
        if (j && !has1) break;
        int node = j ? n1 : n0;
        float* a = j ? a1 : a0;
        float inv = j ? inv1 : inv0;
        uint2 rr = *reinterpret_cast<const uint2*>(C + (size_t)node * S + F + colbase);
        float4 bv = *reinterpret_cast<const float4*>(bias + colbase);
        float v0 = a[0] * inv + bf2f(rr.x & 0xffff) + bv.x;
        float v1 = a[1] * inv + bf2f(rr.x >> 16) + bv.y;
        float v2 = a[2] * inv + bf2f(rr.y & 0xffff) + bv.z;
        float v3 = a[3] * inv + bf2f(rr.y >> 16) + bv.w;
        float m = fmaxf(fmaxf(v0, v1), fmaxf(v2, v3));
        #pragma unroll
        for (int off = 1; off < LPG; off <<= 1) m = fmaxf(m, __shfl_xor(m, off));
        float s = expf(v0 - m) + expf(v1 - m) + expf(v2 - m) + expf(v3 - m);
        #pragma unroll
        for (int off = 1; off < LPG; off <<= 1) s += __shfl_xor(s, off);
        float ls = logf(s);
        if (lane < LPG) {
            *reinterpret_cast<float4*>(hout + (size_t)node * 64 + colbase) =
                make_float4(v0, v1, v2, v3);
            *reinterpret_cast<float4*>(lout + (size_t)node * 64 + colbase) =
                make_float4(v0 - m - ls, v1 - m - ls, v2 - m - ls, v3 - m - ls);
        }
    }
}

extern "C" void kernel_launch(void* const* d_in, const int* in_sizes, int n_in,
                              void* d_out, int out_size, void* d_ws, size_t ws_size,
                              hipStream_t stream) {
    const float* x   = (const float*)d_in[0];
    const int*   ei  = (const int*)d_in[1];
    const float* W1l = (const float*)d_in[2];
    const float* b1  = (const float*)d_in[3];
    const float* W1r = (const float*)d_in[4];
    const float* W2l = (const float*)d_in[5];
    const float* b2  = (const float*)d_in[6];
    const float* W2r = (const float*)d_in[7];
    const float* W3l = (const float*)d_in[8];
    const float* b3  = (const float*)d_in[9];
    const float* W3r = (const float*)d_in[10];
    const int* esrc = ei;
    const int* edst = ei + N_EDGES;

    char* ws = (char*)d_ws;
    size_t off = 0;
    auto alloc = [&](size_t b) { void* p = ws + off; off = (off + b + 255) & ~(size_t)255; return p; };
    ushort_t* Xbf = (ushort_t*)alloc((size_t)MP * 256 * 2);       // later: C3 (bf16 [P3|R3], width 128)
    unsigned char* P1 = (unsigned char*)alloc((size_t)MP * 256);  // fp8; later: P2 (width 128 fp8)
    ushort_t* R1 = (ushort_t*)alloc((size_t)MP * 256 * 2);        // bf16; later: R2 (width 128)
    ushort_t* H1 = (ushort_t*)alloc((size_t)MP * 256 * 2);
    ushort_t* H2 = (ushort_t*)alloc((size_t)MP * 128 * 2);
    int* offs = (int*)alloc((N_NODES + 1) * 4);
    int* cur  = (int*)alloc(N_NODES * 4);
    int* csrc = (int*)alloc(N_EDGES * 4);
    int* bsum = (int*)alloc(256 * 4);
    ushort_t* pB1 = (ushort_t*)alloc(256 * 512 * 2);
    ushort_t* pB2 = (ushort_t*)alloc(256 * 256 * 2);
    ushort_t* pB3 = (ushort_t*)alloc(128 * 128 * 2);

    unsigned char* P2 = P1;           // alias (P1 dead after agg1)
    ushort_t* R2 = R1;                // alias (R1 dead after agg1)
    ushort_t* C3 = Xbf;               // alias (Xbf dead after gemm1)

    int nScanBlocks = (N_NODES + 255) / 256;  // 196

    // CSR build (reused by all 3 layers)
    hipMemsetAsync(cur, 0, N_NODES * 4, stream);
    deg_k<<<(N_EDGES + 255) / 256, 256, 0, stream>>>(edst, cur, N_EDGES);
    scan1_k<<<nScanBlocks, 256, 0, stream>>>(cur, offs, bsum, N_NODES);
    scan2_k<<<1, 256, 0, stream>>>(bsum, nScanBlocks);
    scan3_k<<<nScanBlocks, 256, 0, stream>>>(offs, bsum, N_NODES, N_EDGES);
    hipMemcpyAsync(cur, offs, N_NODES * 4, hipMemcpyDeviceToDevice, stream);
    scat_k<<<(N_EDGES + 255) / 256, 256, 0, stream>>>(esrc, edst, cur, csrc, N_EDGES);

    // x -> bf16
    cvt_k<<<(int)(((long long)N_NODES * 256 / 4 + 255) / 256), 256, 0, stream>>>(
        x, Xbf, (long long)N_NODES * 256);

    // pack weight pairs [Wl|Wr]
    pack2_k<<<(16384 + 255) / 256, 256, 0, stream>>>(W1l, W1r, pB1, 256, 256);
    pack2_k<<<(8192 + 255) / 256, 256, 0, stream>>>(W2l, W2r, pB2, 256, 128);
    pack2_k<<<(2048 + 255) / 256, 256, 0, stream>>>(W3l, W3r, pB3, 128, 64);

    int gemmGrid = MP / 32;                    // 1564 blocks (32 rows each)
    int aggGrid = ((N_NODES + 1) / 2 + 3) / 4; // 6250 blocks (2 nodes/wave, 4 waves)
    float* hout = (float*)d_out;
    float* lout = hout + (long long)N_NODES * 64;

    // layer 1: P1(fp8) | R1(bf16) = Xbf @ [W1l|W1r]; h1 = relu(mean(P1) + R1 + b1)
    gemm_k<256, 512, 256><<<gemmGrid, 256, 0, stream>>>(Xbf, pB1, P1, R1);
    aggP8_k<256><<<aggGrid, 256, 0, stream>>>(P1, offs, csrc, R1, b1, H1, N_NODES);
    // layer 2
    gemm_k<256, 256, 128><<<gemmGrid, 256, 0, stream>>>(H1, pB2, P2, R2);
    aggP8_k<128><<<aggGrid, 256, 0, stream>>>(P2, offs, csrc, R2, b2, H2, N_NODES);
    // layer 3: C3 = [P3|R3] bf16; fused mean + bias + log_softmax
    gemm_k<128, 128, 0><<<gemmGrid, 256, 0, stream>>>(H2, pB3, nullptr, C3);
    aggF_k<<<aggGrid, 256, 0, stream>>>(C3, offs, csrc, b3, hout, lout, N_NODES);
}

// Round 7
// 301.800 us; speedup vs baseline: 1.7715x; 1.0228x over previous
//
#include <hip/hip_runtime.h>
#include <hip/hip_bf16.h>

#define N_NODES 50000
#define N_EDGES 800000
#define MP 50048  // N_NODES padded to multiple of 64

typedef unsigned short ushort_t;
typedef unsigned int uint_t;
typedef __attribute__((ext_vector_type(8))) __bf16 bf16x8;
typedef __attribute__((ext_vector_type(4))) float f32x4;
typedef __attribute__((ext_vector_type(2))) float f32x2;

__device__ __forceinline__ float bf2f(uint_t u) {
    union { uint_t i; float f; } v; v.i = u << 16; return v.f;
}
__device__ __forceinline__ ushort_t f2bf(float f) {
    union { float f; uint_t i; } v; v.f = f;
    uint_t u = v.i;
    return (ushort_t)((u + 0x7FFFu + ((u >> 16) & 1u)) >> 16);
}
// accumulate 8 fp8 (e4m3) values held in a uint2
__device__ __forceinline__ void accf8(float* a, uint2 d) {
    f32x2 p;
    p = __builtin_amdgcn_cvt_pk_f32_fp8(d.x, false); a[0] += p.x; a[1] += p.y;
    p = __builtin_amdgcn_cvt_pk_f32_fp8(d.x, true);  a[2] += p.x; a[3] += p.y;
    p = __builtin_amdgcn_cvt_pk_f32_fp8(d.y, false); a[4] += p.x; a[5] += p.y;
    p = __builtin_amdgcn_cvt_pk_f32_fp8(d.y, true);  a[6] += p.x; a[7] += p.y;
}
// pack high halves of two f32 -> two bf16 (truncation)
__device__ __forceinline__ uint_t pk_hi(float a, float b) {
    return __builtin_amdgcn_perm(__float_as_uint(b), __float_as_uint(a), 0x07060302);
}

// ---------------- CSR build ----------------
__global__ void deg_k(const int* __restrict__ dst, int* __restrict__ deg, int E) {
    int e = blockIdx.x * 256 + threadIdx.x;
    if (e < E) atomicAdd(&deg[dst[e]], 1);
}

__global__ void scan1_k(const int* __restrict__ deg, int* __restrict__ offs,
                        int* __restrict__ bsum, int n) {
    __shared__ int s[256];
    int i = blockIdx.x * 256 + threadIdx.x;
    int v = (i < n) ? deg[i] : 0;
    s[threadIdx.x] = v;
    __syncthreads();
    #pragma unroll
    for (int d = 1; d < 256; d <<= 1) {
        int t = (threadIdx.x >= d) ? s[threadIdx.x - d] : 0;
        __syncthreads();
        s[threadIdx.x] += t;
        __syncthreads();
    }
    if (i < n) offs[i] = s[threadIdx.x] - v;   // exclusive
    if (threadIdx.x == 255) bsum[blockIdx.x] = s[255];
}

__global__ void scan2_k(int* __restrict__ bsum, int nb) {  // single block
    __shared__ int s[256];
    int v = (threadIdx.x < nb) ? bsum[threadIdx.x] : 0;
    s[threadIdx.x] = v;
    __syncthreads();
    #pragma unroll
    for (int d = 1; d < 256; d <<= 1) {
        int t = (threadIdx.x >= d) ? s[threadIdx.x - d] : 0;
        __syncthreads();
        s[threadIdx.x] += t;
        __syncthreads();
    }
    if (threadIdx.x < nb) bsum[threadIdx.x] = s[threadIdx.x] - v;  // exclusive
}

__global__ void scan3_k(int* __restrict__ offs, const int* __restrict__ bsum,
                        int* __restrict__ cur, int n, int E) {
    int i = blockIdx.x * 256 + threadIdx.x;
    if (i < n) {
        int v = offs[i] + bsum[blockIdx.x];
        offs[i] = v;
        cur[i] = v;
    }
    if (i == 0) offs[n] = E;
}

__global__ void scat_k(const int* __restrict__ src, const int* __restrict__ dst,
                       int* __restrict__ cur, ushort_t* __restrict__ csrc, int E) {
    int e = blockIdx.x * 256 + threadIdx.x;
    if (e < E) {
        int p = atomicAdd(&cur[dst[e]], 1);
        csrc[p] = (ushort_t)src[e];
    }
}

// ---------------- fused weight packing (all 3 layers) into MFMA frag order ----------------
// frag (kt, ct): value(lane, j) = W[kt*32 + (lane>>4)*8 + j][ct*16 + (lane&15)]
__device__ __forceinline__ void pack_one(const float* Wl, const float* Wr,
                                         ushort_t* P, int K, int F, int t) {
    int NOUT = 2 * F;
    int lane = t & 63;
    int frag = t >> 6;
    int nct = NOUT / 16;
    int ct = frag % nct;
    int kt = frag / nct;
    int col = ct * 16 + (lane & 15);
    const float* W = (col < F) ? Wl : Wr;
    int c = (col < F) ? col : col - F;
    int k0 = kt * 32 + (lane >> 4) * 8;
    uint_t w[4];
    #pragma unroll
    for (int p = 0; p < 4; ++p) {
        ushort_t lo = f2bf(W[(size_t)(k0 + 2 * p) * F + c]);
        ushort_t hi = f2bf(W[(size_t)(k0 + 2 * p + 1) * F + c]);
        w[p] = (uint_t)lo | ((uint_t)hi << 16);
    }
    *(reinterpret_cast<uint4*>(P) + t) = make_uint4(w[0], w[1], w[2], w[3]);
}

__global__ void pack_all_k(const float* __restrict__ W1l, const float* __restrict__ W1r,
                           const float* __restrict__ W2l, const float* __restrict__ W2r,
                           const float* __restrict__ W3l, const float* __restrict__ W3r,
                           ushort_t* __restrict__ pB1, ushort_t* __restrict__ pB2,
                           ushort_t* __restrict__ pB3) {
    int tid = blockIdx.x * 256 + threadIdx.x;
    if (tid < 16384)       pack_one(W1l, W1r, pB1, 256, 256, tid);
    else if (tid < 24576)  pack_one(W2l, W2r, pB2, 256, 128, tid - 16384);
    else if (tid < 26624)  pack_one(W3l, W3r, pB3, 128, 64, tid - 24576);
}

// ---------------- GEMM (operand-swapped): [P|R] = A[MP,K] @ Bp ----------------
// Weight frag as MFMA A-operand, x frag as B-operand -> thread holds 4 consecutive
// output cols of one row -> packed u32 (4xfp8) / uint2 (4xbf16) stores.
// F32A: read f32 activations directly, truncate-pack to bf16 (row clamped to nvalid).
template <int K, int NOUT, int PF, bool F32A>
__global__ __launch_bounds__(256) void gemm_k(
    const void* __restrict__ Av, const ushort_t* __restrict__ Bp,
    unsigned char* __restrict__ Pout, ushort_t* __restrict__ Rout, int nvalid) {
    constexpr int KT = K / 32;
    constexpr int CTW = NOUT / 64;   // col-tiles per wave
    constexpr int RS = NOUT - PF;    // R row stride
    constexpr int RB = 4;            // 64 rows per block
    int wave = threadIdx.x >> 6;
    int lane = threadIdx.x & 63;
    int rowBase = blockIdx.x * (16 * RB);
    int arowoff = lane & 15;
    int kgrp = (lane >> 4) * 8;
    int ct0 = wave * CTW;

    f32x4 acc[RB][CTW];
    #pragma unroll
    for (int r = 0; r < RB; ++r)
        #pragma unroll
        for (int c = 0; c < CTW; ++c) acc[r][c] = (f32x4){0.f, 0.f, 0.f, 0.f};

    #pragma unroll
    for (int kt = 0; kt < KT; ++kt) {
        bf16x8 xf[RB];
        #pragma unroll
        for (int r = 0; r < RB; ++r) {
            int row = rowBase + r * 16 + arowoff;
            if (F32A) {
                row = min(row, nvalid - 1);
                const float* A = (const float*)Av;
                const float* p = A + (size_t)row * K + kt * 32 + kgrp;
                float4 f0 = *reinterpret_cast<const float4*>(p);
                float4 f1 = *reinterpret_cast<const float4*>(p + 4);
                union { uint_t u[4]; bf16x8 v; } cv;
                cv.u[0] = pk_hi(f0.x, f0.y);
                cv.u[1] = pk_hi(f0.z, f0.w);
                cv.u[2] = pk_hi(f1.x, f1.y);
                cv.u[3] = pk_hi(f1.z, f1.w);
                xf[r] = cv.v;
            } else {
                const ushort_t* A = (const ushort_t*)Av;
                xf[r] = *reinterpret_cast<const bf16x8*>(A + (size_t)row * K + kt * 32 + kgrp);
            }
        }
        #pragma unroll
        for (int ct = 0; ct < CTW; ++ct) {
            bf16x8 wf = *reinterpret_cast<const bf16x8*>(
                Bp + ((size_t)(kt * (NOUT / 16) + ct0 + ct) * 64 + lane) * 8);
            #pragma unroll
            for (int r = 0; r < RB; ++r)
                acc[r][ct] = __builtin_amdgcn_mfma_f32_16x16x32_bf16(wf, xf[r], acc[r][ct], 0, 0, 0);
        }
    }

    int r0 = (lane >> 4) * 4;   // wcol sub-offset
    #pragma unroll
    for (int r = 0; r < RB; ++r) {
        int xrow = rowBase + r * 16 + arowoff;
        #pragma unroll
        for (int ct = 0; ct < CTW; ++ct) {
            int wc = (ct0 + ct) * 16 + r0;
            f32x4 v = acc[r][ct];
            if (PF > 0 && wc < PF) {
                uint_t u = __builtin_amdgcn_cvt_pk_fp8_f32(v[0], v[1], 0u, false);
                u = __builtin_amdgcn_cvt_pk_fp8_f32(v[2], v[3], u, true);
                *reinterpret_cast<uint_t*>(Pout + (size_t)xrow * PF + wc) = u;
            } else {
                uint2 w;
                w.x = (uint_t)f2bf(v[0]) | ((uint_t)f2bf(v[1]) << 16);
                w.y = (uint_t)f2bf(v[2]) | ((uint_t)f2bf(v[3]) << 16);
                *reinterpret_cast<uint2*>(Rout + (size_t)xrow * RS + (wc - PF)) = w;
            }
        }
    }
}

// ---------------- fused aggregate (fp8 P) + epilogue, 2 nodes/wave ----------------
// !FINAL: H = relu(mean(P) + R + bias) bf16.
// FINAL (F=64): h = mean(P) + R + bias -> hout f32; fused log_softmax -> lout.
template <int F, bool FINAL>
__global__ __launch_bounds__(256) void aggP8_k(
    const unsigned char* __restrict__ P, const int* __restrict__ offs,
    const ushort_t* __restrict__ csrc, const ushort_t* __restrict__ R,
    const float* __restrict__ bias, ushort_t* __restrict__ H,
    float* __restrict__ hout, float* __restrict__ lout, int n) {
    constexpr int LPG = F / 8;            // 32, 16, 8 lanes cover a row (8B each)
    constexpr int G = 64 / LPG;           // 2, 4, 8 edge groups
    constexpr int U = (G >= 4) ? 1 : (4 / G);
    constexpr int ST = G * U;             // edges consumed per iter per node
    int wid = (blockIdx.x * 256 + threadIdx.x) >> 6;
    int lane = threadIdx.x & 63;
    int g = lane / LPG;
    int sub = lane & (LPG - 1);
    int colbase = sub * 8;
    int n0 = 2 * wid, n1 = 2 * wid + 1;
    if (n0 >= n) return;
    bool has1 = (n1 < n);
    int b0 = offs[n0], end0 = offs[n0 + 1];
    int b1 = has1 ? offs[n1] : 0, end1 = has1 ? offs[n1 + 1] : 0;

    float a0[8] = {0,0,0,0,0,0,0,0};
    float a1[8] = {0,0,0,0,0,0,0,0};
    int e0 = b0, e1 = b1;
    const unsigned char* Pc = P + colbase;

    while (e0 + ST <= end0 && e1 + ST <= end1) {
        uint2 d0[U], d1[U];
        #pragma unroll
        for (int u = 0; u < U; ++u) {
            int s = csrc[e0 + g + u * G];
            d0[u] = *reinterpret_cast<const uint2*>(Pc + (size_t)s * F);
        }
        #pragma unroll
        for (int u = 0; u < U; ++u) {
            int s = csrc[e1 + g + u * G];
            d1[u] = *reinterpret_cast<const uint2*>(Pc + (size_t)s * F);
        }
        #pragma unroll
        for (int u = 0; u < U; ++u) { accf8(a0, d0[u]); accf8(a1, d1[u]); }
        e0 += ST; e1 += ST;
    }
    while (e0 + ST <= end0) {
        uint2 d[U];
        #pragma unroll
        for (int u = 0; u < U; ++u) {
            int s = csrc[e0 + g + u * G];
            d[u] = *reinterpret_cast<const uint2*>(Pc + (size_t)s * F);
        }
        #pragma unroll
        for (int u = 0; u < U; ++u) accf8(a0, d[u]);
        e0 += ST;
    }
    for (int e = e0 + g; e < end0; e += G) {
        int s = csrc[e];
        uint2 d = *reinterpret_cast<const uint2*>(Pc + (size_t)s * F);
        accf8(a0, d);
    }
    while (e1 + ST <= end1) {
        uint2 d[U];
        #pragma unroll
        for (int u = 0; u < U; ++u) {
            int s = csrc[e1 + g + u * G];
            d[u] = *reinterpret_cast<const uint2*>(Pc + (size_t)s * F);
        }
        #pragma unroll
        for (int u = 0; u < U; ++u) accf8(a1, d[u]);
        e1 += ST;
    }
    for (int e = e1 + g; e < end1; e += G) {
        int s = csrc[e];
        uint2 d = *reinterpret_cast<const uint2*>(Pc + (size_t)s * F);
        accf8(a1, d);
    }

    // combine the G edge-groups: afterwards ALL lanes hold node totals
    #pragma unroll
    for (int off = LPG; off < 64; off <<= 1) {
        #pragma unroll
        for (int i = 0; i < 8; ++i) {
            a0[i] += __shfl_xor(a0[i], off);
            a1[i] += __shfl_xor(a1[i], off);
        }
    }

    float inv0 = 1.f / fmaxf((float)(end0 - b0), 1.f);
    float inv1 = 1.f / fmaxf((float)(end1 - b1), 1.f);

    #pragma unroll
    for (int j = 0; j < 2; ++j) {
        if (j && !has1) break;
        int node = j ? n1 : n0;
        float* a = j ? a1 : a0;
        float inv = j ? inv1 : inv0;
        uint4 rr = *reinterpret_cast<const uint4*>(R + (size_t)node * F + colbase);
        float r[8];
        r[0] = bf2f(rr.x & 0xffff); r[1] = bf2f(rr.x >> 16);
        r[2] = bf2f(rr.y & 0xffff); r[3] = bf2f(rr.y >> 16);
        r[4] = bf2f(rr.z & 0xffff); r[5] = bf2f(rr.z >> 16);
        r[6] = bf2f(rr.w & 0xffff); r[7] = bf2f(rr.w >> 16);
        float4 bA = *reinterpret_cast<const float4*>(bias + colbase);
        float4 bB = *reinterpret_cast<const float4*>(bias + colbase + 4);
        float bv[8] = {bA.x, bA.y, bA.z, bA.w, bB.x, bB.y, bB.z, bB.w};
        float v[8];
        #pragma unroll
        for (int i = 0; i < 8; ++i) v[i] = a[i] * inv + r[i] + bv[i];

        if constexpr (!FINAL) {
            if (lane < LPG) {
                uint_t w[4];
                #pragma unroll
                for (int p = 0; p < 4; ++p) {
                    float v0 = fmaxf(v[2 * p], 0.f);
                    float v1 = fmaxf(v[2 * p + 1], 0.f);
                    w[p] = (uint_t)f2bf(v0) | ((uint_t)f2bf(v1) << 16);
                }
                *reinterpret_cast<uint4*>(H + (size_t)node * F + colbase) =
                    make_uint4(w[0], w[1], w[2], w[3]);
            }
        } else {
            // log_softmax over the 64 cols (8 lanes x 8 cols)
            float m = v[0];
            #pragma unroll
            for (int i = 1; i < 8; ++i) m = fmaxf(m, v[i]);
            #pragma unroll
            for (int off = 1; off < LPG; off <<= 1) m = fmaxf(m, __shfl_xor(m, off));
            float s = 0.f;
            #pragma unroll
            for (int i = 0; i < 8; ++i) s += expf(v[i] - m);
            #pragma unroll
            for (int off = 1; off < LPG; off <<= 1) s += __shfl_xor(s, off);
            float ls = m + logf(s);
            if (lane < LPG) {
                float* ho = hout + (size_t)node * 64 + colbase;
                float* lo = lout + (size_t)node * 64 + colbase;
                *reinterpret_cast<float4*>(ho) = make_float4(v[0], v[1], v[2], v[3]);
                *reinterpret_cast<float4*>(ho + 4) = make_float4(v[4], v[5], v[6], v[7]);
                *reinterpret_cast<float4*>(lo) =
                    make_float4(v[0] - ls, v[1] - ls, v[2] - ls, v[3] - ls);
                *reinterpret_cast<float4*>(lo + 4) =
                    make_float4(v[4] - ls, v[5] - ls, v[6] - ls, v[7] - ls);
            }
        }
    }
}

extern "C" void kernel_launch(void* const* d_in, const int* in_sizes, int n_in,
                              void* d_out, int out_size, void* d_ws, size_t ws_size,
                              hipStream_t stream) {
    const float* x   = (const float*)d_in[0];
    const int*   ei  = (const int*)d_in[1];
    const float* W1l = (const float*)d_in[2];
    const float* b1  = (const float*)d_in[3];
    const float* W1r = (const float*)d_in[4];
    const float* W2l = (const float*)d_in[5];
    const float* b2  = (const float*)d_in[6];
    const float* W2r = (const float*)d_in[7];
    const float* W3l = (const float*)d_in[8];
    const float* b3  = (const float*)d_in[9];
    const float* W3r = (const float*)d_in[10];
    const int* esrc = ei;
    const int* edst = ei + N_EDGES;

    char* ws = (char*)d_ws;
    size_t off = 0;
    auto alloc = [&](size_t b) { void* p = ws + off; off = (off + b + 255) & ~(size_t)255; return p; };
    unsigned char* P1 = (unsigned char*)alloc((size_t)MP * 256);  // fp8; reused as P2/P3
    ushort_t* R1 = (ushort_t*)alloc((size_t)MP * 256 * 2);        // bf16; reused as R2/R3
    ushort_t* H1 = (ushort_t*)alloc((size_t)MP * 256 * 2);
    ushort_t* H2 = (ushort_t*)alloc((size_t)MP * 128 * 2);
    int* offs = (int*)alloc((N_NODES + 1) * 4);
    int* cur  = (int*)alloc(N_NODES * 4);
    int* dcnt = (int*)alloc(N_NODES * 4);
    ushort_t* csrc = (ushort_t*)alloc(N_EDGES * 2);
    int* bsum = (int*)alloc(256 * 4);
    ushort_t* pB1 = (ushort_t*)alloc(256 * 512 * 2);
    ushort_t* pB2 = (ushort_t*)alloc(256 * 256 * 2);
    ushort_t* pB3 = (ushort_t*)alloc(128 * 128 * 2);

    unsigned char* P2 = P1;
    ushort_t* R2 = R1;
    unsigned char* P3 = P1;
    ushort_t* R3 = R1;

    int nScanBlocks = (N_NODES + 255) / 256;  // 196

    // CSR build (reused by all 3 layers)
    hipMemsetAsync(dcnt, 0, N_NODES * 4, stream);
    deg_k<<<(N_EDGES + 255) / 256, 256, 0, stream>>>(edst, dcnt, N_EDGES);
    scan1_k<<<nScanBlocks, 256, 0, stream>>>(dcnt, offs, bsum, N_NODES);
    scan2_k<<<1, 256, 0, stream>>>(bsum, nScanBlocks);
    scan3_k<<<nScanBlocks, 256, 0, stream>>>(offs, bsum, cur, N_NODES, N_EDGES);
    scat_k<<<(N_EDGES + 255) / 256, 256, 0, stream>>>(esrc, edst, cur, csrc, N_EDGES);

    // pack all weight pairs [Wl|Wr]
    pack_all_k<<<(26624 + 255) / 256, 256, 0, stream>>>(
        W1l, W1r, W2l, W2r, W3l, W3r, pB1, pB2, pB3);

    int gemmGrid = MP / 64;                    // 782 blocks (64 rows each)
    int aggGrid = ((N_NODES + 1) / 2 + 3) / 4; // 6250 blocks (2 nodes/wave, 4 waves)
    float* hout = (float*)d_out;
    float* lout = hout + (size_t)N_NODES * 64;

    // layer 1: P1(fp8)|R1(bf16) = x(f32) @ [W1l|W1r]; h1 = relu(mean(P1)+R1+b1)
    gemm_k<256, 512, 256, true><<<gemmGrid, 256, 0, stream>>>(x, pB1, P1, R1, N_NODES);
    aggP8_k<256, false><<<aggGrid, 256, 0, stream>>>(
        P1, offs, csrc, R1, b1, H1, nullptr, nullptr, N_NODES);
    // layer 2
    gemm_k<256, 256, 128, false><<<gemmGrid, 256, 0, stream>>>(H1, pB2, P2, R2, N_NODES);
    aggP8_k<128, false><<<aggGrid, 256, 0, stream>>>(
        P2, offs, csrc, R2, b2, H2, nullptr, nullptr, N_NODES);
    // layer 3: P3(fp8)|R3(bf16) = H2 @ [W3l|W3r]; fused mean+bias+log_softmax
    gemm_k<128, 128, 64, false><<<gemmGrid, 256, 0, stream>>>(H2, pB3, P3, R3, N_NODES);
    aggP8_k<64, true><<<aggGrid, 256, 0, stream>>>(
        P3, offs, csrc, R3, b3, nullptr, hout, lout, N_NODES);
}

// Round 9
// 261.047 us; speedup vs baseline: 2.0480x; 1.1561x over previous
//
#include <hip/hip_runtime.h>
#include <hip/hip_bf16.h>

#define N_NODES 50000
#define N_EDGES 800000
#define MP 50048  // N_NODES padded to multiple of 64

typedef unsigned short ushort_t;
typedef unsigned int uint_t;
typedef __attribute__((ext_vector_type(8))) __bf16 bf16x8;
typedef __attribute__((ext_vector_type(4))) float f32x4;
typedef __attribute__((ext_vector_type(2))) float f32x2;

__device__ __forceinline__ float bf2f(uint_t u) {
    union { uint_t i; float f; } v; v.i = u << 16; return v.f;
}
__device__ __forceinline__ ushort_t f2bf(float f) {
    union { float f; uint_t i; } v; v.f = f;
    uint_t u = v.i;
    return (ushort_t)((u + 0x7FFFu + ((u >> 16) & 1u)) >> 16);
}
// accumulate 8 fp8 (e4m3) values held in a uint2
__device__ __forceinline__ void accf8(float* a, uint2 d) {
    f32x2 p;
    p = __builtin_amdgcn_cvt_pk_f32_fp8(d.x, false); a[0] += p.x; a[1] += p.y;
    p = __builtin_amdgcn_cvt_pk_f32_fp8(d.x, true);  a[2] += p.x; a[3] += p.y;
    p = __builtin_amdgcn_cvt_pk_f32_fp8(d.y, false); a[4] += p.x; a[5] += p.y;
    p = __builtin_amdgcn_cvt_pk_f32_fp8(d.y, true);  a[6] += p.x; a[7] += p.y;
}
// pack high halves of two f32 -> two bf16 (truncation)
__device__ __forceinline__ uint_t pk_hi(float a, float b) {
    return __builtin_amdgcn_perm(__float_as_uint(b), __float_as_uint(a), 0x07060302);
}

// ---------------- CSR build ----------------
__global__ void deg_k(const int* __restrict__ dst, int* __restrict__ deg, int E) {
    int e = blockIdx.x * 256 + threadIdx.x;
    if (e < E) atomicAdd(&deg[dst[e]], 1);
}

__global__ void scan1_k(const int* __restrict__ deg, int* __restrict__ offs,
                        int* __restrict__ bsum, int n) {
    __shared__ int s[256];
    int i = blockIdx.x * 256 + threadIdx.x;
    int v = (i < n) ? deg[i] : 0;
    s[threadIdx.x] = v;
    __syncthreads();
    #pragma unroll
    for (int d = 1; d < 256; d <<= 1) {
        int t = (threadIdx.x >= d) ? s[threadIdx.x - d] : 0;
        __syncthreads();
        s[threadIdx.x] += t;
        __syncthreads();
    }
    if (i < n) offs[i] = s[threadIdx.x] - v;   // exclusive
    if (threadIdx.x == 255) bsum[blockIdx.x] = s[255];
}

__global__ void scan2_k(int* __restrict__ bsum, int nb) {  // single block
    __shared__ int s[256];
    int v = (threadIdx.x < nb) ? bsum[threadIdx.x] : 0;
    s[threadIdx.x] = v;
    __syncthreads();
    #pragma unroll
    for (int d = 1; d < 256; d <<= 1) {
        int t = (threadIdx.x >= d) ? s[threadIdx.x - d] : 0;
        __syncthreads();
        s[threadIdx.x] += t;
        __syncthreads();
    }
    if (threadIdx.x < nb) bsum[threadIdx.x] = s[threadIdx.x] - v;  // exclusive
}

__global__ void scan3_k(int* __restrict__ offs, const int* __restrict__ bsum,
                        int* __restrict__ cur, int n, int E) {
    int i = blockIdx.x * 256 + threadIdx.x;
    if (i < n) {
        int v = offs[i] + bsum[blockIdx.x];
        offs[i] = v;
        cur[i] = v;
    }
    if (i == 0) offs[n] = E;
}

__global__ void scat_k(const int* __restrict__ src, const int* __restrict__ dst,
                       int* __restrict__ cur, ushort_t* __restrict__ csrc, int E) {
    int e = blockIdx.x * 256 + threadIdx.x;
    if (e < E) {
        int p = atomicAdd(&cur[dst[e]], 1);
        csrc[p] = (ushort_t)src[e];
    }
}

// ---------------- fused weight packing (all 3 layers) into MFMA frag order ----------------
// frag (kt, ct): value(lane, j) = W[kt*32 + (lane>>4)*8 + j][ct*16 + (lane&15)]
__device__ __forceinline__ void pack_one(const float* Wl, const float* Wr,
                                         ushort_t* P, int K, int F, int t) {
    int NOUT = 2 * F;
    int lane = t & 63;
    int frag = t >> 6;
    int nct = NOUT / 16;
    int ct = frag % nct;
    int kt = frag / nct;
    int col = ct * 16 + (lane & 15);
    const float* W = (col < F) ? Wl : Wr;
    int c = (col < F) ? col : col - F;
    int k0 = kt * 32 + (lane >> 4) * 8;
    uint_t w[4];
    #pragma unroll
    for (int p = 0; p < 4; ++p) {
        ushort_t lo = f2bf(W[(size_t)(k0 + 2 * p) * F + c]);
        ushort_t hi = f2bf(W[(size_t)(k0 + 2 * p + 1) * F + c]);
        w[p] = (uint_t)lo | ((uint_t)hi << 16);
    }
    *(reinterpret_cast<uint4*>(P) + t) = make_uint4(w[0], w[1], w[2], w[3]);
}

__global__ void pack_all_k(const float* __restrict__ W1l, const float* __restrict__ W1r,
                           const float* __restrict__ W2l, const float* __restrict__ W2r,
                           const float* __restrict__ W3l, const float* __restrict__ W3r,
                           ushort_t* __restrict__ pB1, ushort_t* __restrict__ pB2,
                           ushort_t* __restrict__ pB3) {
    int tid = blockIdx.x * 256 + threadIdx.x;
    if (tid < 16384)       pack_one(W1l, W1r, pB1, 256, 256, tid);
    else if (tid < 24576)  pack_one(W2l, W2r, pB2, 256, 128, tid - 16384);
    else if (tid < 26624)  pack_one(W3l, W3r, pB3, 128, 64, tid - 24576);
}

// ---------------- GEMM (operand-swapped, LDS-staged A): [P|R] = A[MP,K] @ Bp ----------------
// 32 rows/block staged once into LDS (padded rows -> bank-balanced ds_read_b128),
// shared by all 4 waves (each wave owns NOUT/4 cols). Weight frag as MFMA A-operand,
// x frag as B-operand -> thread holds 4 consecutive output cols of one row ->
// packed u32 (4xfp8) / uint2 (4xbf16) stores.
// F32A: stage f32 activations with fused truncate-pack to bf16 (rows clamped).
template <int K, int NOUT, int PF, bool F32A>
__global__ __launch_bounds__(256) void gemm_k(
    const void* __restrict__ Av, const ushort_t* __restrict__ Bp,
    unsigned char* __restrict__ Pout, ushort_t* __restrict__ Rout, int nvalid) {
    constexpr int KT = K / 32;
    constexpr int CTW = NOUT / 64;   // col-tiles per wave
    constexpr int RS = NOUT - PF;    // R row stride
    constexpr int ROWS = 32;
    constexpr int PADE = K + 8;      // padded row length (elems) -> 2-way-free banks
    __shared__ ushort_t Atile[ROWS * PADE];

    int rowBase = blockIdx.x * ROWS;

    // ---- stage A tile: 8 threads/row, K/8 elems (K/4 bytes) each ----
    {
        constexpr int NWR = K / 64;              // 16B chunks per thread (4 or 2)
        int srow = threadIdx.x >> 3;
        int sel = (threadIdx.x & 7) * (K / 8);   // element offset within row
        int grow = min(rowBase + srow, nvalid - 1);
        ushort_t* dst = &Atile[srow * PADE + sel];
        if (F32A) {
            const float* A = (const float*)Av + (size_t)grow * K + sel;
            #pragma unroll
            for (int i = 0; i < NWR; ++i) {
                float4 f0 = *reinterpret_cast<const float4*>(A + i * 8);
                float4 f1 = *reinterpret_cast<const float4*>(A + i * 8 + 4);
                uint4 w;
                w.x = pk_hi(f0.x, f0.y);
                w.y = pk_hi(f0.z, f0.w);
                w.z = pk_hi(f1.x, f1.y);
                w.w = pk_hi(f1.z, f1.w);
                *reinterpret_cast<uint4*>(dst + i * 8) = w;
            }
        } else {
            const ushort_t* A = (const ushort_t*)Av + (size_t)grow * K + sel;
            #pragma unroll
            for (int i = 0; i < NWR; ++i)
                *reinterpret_cast<uint4*>(dst + i * 8) =
                    *reinterpret_cast<const uint4*>(A + i * 8);
        }
    }
    __syncthreads();

    int wave = threadIdx.x >> 6;
    int lane = threadIdx.x & 63;
    int arowoff = lane & 15;
    int ct0 = wave * CTW;

    f32x4 acc[2][CTW];
    #pragma unroll
    for (int r = 0; r < 2; ++r)
        #pragma unroll
        for (int c = 0; c < CTW; ++c) acc[r][c] = (f32x4){0.f, 0.f, 0.f, 0.f};

    const ushort_t* A0 = &Atile[arowoff * PADE + (lane >> 4) * 8];
    const ushort_t* A1 = A0 + 16 * PADE;

    #pragma unroll
    for (int kt = 0; kt < KT; ++kt) {
        bf16x8 x0 = *reinterpret_cast<const bf16x8*>(A0 + kt * 32);
        bf16x8 x1 = *reinterpret_cast<const bf16x8*>(A1 + kt * 32);
        #pragma unroll
        for (int ct = 0; ct < CTW; ++ct) {
            bf16x8 wf = *reinterpret_cast<const bf16x8*>(
                Bp + ((size_t)(kt * (NOUT / 16) + ct0 + ct) * 64 + lane) * 8);
            acc[0][ct] = __builtin_amdgcn_mfma_f32_16x16x32_bf16(wf, x0, acc[0][ct], 0, 0, 0);
            acc[1][ct] = __builtin_amdgcn_mfma_f32_16x16x32_bf16(wf, x1, acc[1][ct], 0, 0, 0);
        }
    }

    int r0 = (lane >> 4) * 4;   // wcol sub-offset
    #pragma unroll
    for (int r = 0; r < 2; ++r) {
        int xrow = rowBase + r * 16 + arowoff;
        #pragma unroll
        for (int ct = 0; ct < CTW; ++ct) {
            int wc = (ct0 + ct) * 16 + r0;
            f32x4 v = acc[r][ct];
            if (PF > 0 && wc < PF) {
                uint_t u = __builtin_amdgcn_cvt_pk_fp8_f32(v[0], v[1], 0u, false);
                u = __builtin_amdgcn_cvt_pk_fp8_f32(v[2], v[3], u, true);
                *reinterpret_cast<uint_t*>(Pout + (size_t)xrow * PF + wc) = u;
            } else {
                uint2 w;
                w.x = (uint_t)f2bf(v[0]) | ((uint_t)f2bf(v[1]) << 16);
                w.y = (uint_t)f2bf(v[2]) | ((uint_t)f2bf(v[3]) << 16);
                *reinterpret_cast<uint2*>(Rout + (size_t)xrow * RS + (wc - PF)) = w;
            }
        }
    }
}

// ---------------- fused aggregate (fp8 P) + epilogue, 2 nodes/wave ----------------
// !FINAL: H = relu(mean(P) + R + bias) bf16.
// FINAL (F=64): h = mean(P) + R + bias -> hout f32; fused log_softmax -> lout.
template <int F, bool FINAL>
__global__ __launch_bounds__(256) void aggP8_k(
    const unsigned char* __restrict__ P, const int* __restrict__ offs,
    const ushort_t* __restrict__ csrc, const ushort_t* __restrict__ R,
    const float* __restrict__ bias, ushort_t* __restrict__ H,
    float* __restrict__ hout, float* __restrict__ lout, int n) {
    constexpr int LPG = F / 8;            // 32, 16, 8 lanes cover a row (8B each)
    constexpr int G = 64 / LPG;           // 2, 4, 8 edge groups
    constexpr int U = (G >= 4) ? 1 : (4 / G);
    constexpr int ST = G * U;             // edges consumed per iter per node
    int wid = (blockIdx.x * 256 + threadIdx.x) >> 6;
    int lane = threadIdx.x & 63;
    int g = lane / LPG;
    int sub = lane & (LPG - 1);
    int colbase = sub * 8;
    int n0 = 2 * wid, n1 = 2 * wid + 1;
    if (n0 >= n) return;
    bool has1 = (n1 < n);
    int b0 = offs[n0], end0 = offs[n0 + 1];
    int b1 = has1 ? offs[n1] : 0, end1 = has1 ? offs[n1 + 1] : 0;

    float a0[8] = {0,0,0,0,0,0,0,0};
    float a1[8] = {0,0,0,0,0,0,0,0};
    int e0 = b0, e1 = b1;
    const unsigned char* Pc = P + colbase;

    while (e0 + ST <= end0 && e1 + ST <= end1) {
        uint2 d0[U], d1[U];
        #pragma unroll
        for (int u = 0; u < U; ++u) {
            int s = csrc[e0 + g + u * G];
            d0[u] = *reinterpret_cast<const uint2*>(Pc + (size_t)s * F);
        }
        #pragma unroll
        for (int u = 0; u < U; ++u) {
            int s = csrc[e1 + g + u * G];
            d1[u] = *reinterpret_cast<const uint2*>(Pc + (size_t)s * F);
        }
        #pragma unroll
        for (int u = 0; u < U; ++u) { accf8(a0, d0[u]); accf8(a1, d1[u]); }
        e0 += ST; e1 += ST;
    }
    while (e0 + ST <= end0) {
        uint2 d[U];
        #pragma unroll
        for (int u = 0; u < U; ++u) {
            int s = csrc[e0 + g + u * G];
            d[u] = *reinterpret_cast<const uint2*>(Pc + (size_t)s * F);
        }
        #pragma unroll
        for (int u = 0; u < U; ++u) accf8(a0, d[u]);
        e0 += ST;
    }
    for (int e = e0 + g; e < end0; e += G) {
        int s = csrc[e];
        uint2 d = *reinterpret_cast<const uint2*>(Pc + (size_t)s * F);
        accf8(a0, d);
    }
    while (e1 + ST <= end1) {
        uint2 d[U];
        #pragma unroll
        for (int u = 0; u < U; ++u) {
            int s = csrc[e1 + g + u * G];
            d[u] = *reinterpret_cast<const uint2*>(Pc + (size_t)s * F);
        }
        #pragma unroll
        for (int u = 0; u < U; ++u) accf8(a1, d[u]);
        e1 += ST;
    }
    for (int e = e1 + g; e < end1; e += G) {
        int s = csrc[e];
        uint2 d = *reinterpret_cast<const uint2*>(Pc + (size_t)s * F);
        accf8(a1, d);
    }

    // combine the G edge-groups: afterwards ALL lanes hold node totals
    #pragma unroll
    for (int off = LPG; off < 64; off <<= 1) {
        #pragma unroll
        for (int i = 0; i < 8; ++i) {
            a0[i] += __shfl_xor(a0[i], off);
            a1[i] += __shfl_xor(a1[i], off);
        }
    }

    float inv0 = 1.f / fmaxf((float)(end0 - b0), 1.f);
    float inv1 = 1.f / fmaxf((float)(end1 - b1), 1.f);

    #pragma unroll
    for (int j = 0; j < 2; ++j) {
        if (j && !has1) break;
        int node = j ? n1 : n0;
        float* a = j ? a1 : a0;
        float inv = j ? inv1 : inv0;
        uint4 rr = *reinterpret_cast<const uint4*>(R + (size_t)node * F + colbase);
        float r[8];
        r[0] = bf2f(rr.x & 0xffff); r[1] = bf2f(rr.x >> 16);
        r[2] = bf2f(rr.y & 0xffff); r[3] = bf2f(rr.y >> 16);
        r[4] = bf2f(rr.z & 0xffff); r[5] = bf2f(rr.z >> 16);
        r[6] = bf2f(rr.w & 0xffff); r[7] = bf2f(rr.w >> 16);
        float4 bA = *reinterpret_cast<const float4*>(bias + colbase);
        float4 bB = *reinterpret_cast<const float4*>(bias + colbase + 4);
        float bv[8] = {bA.x, bA.y, bA.z, bA.w, bB.x, bB.y, bB.z, bB.w};
        float v[8];
        #pragma unroll
        for (int i = 0; i < 8; ++i) v[i] = a[i] * inv + r[i] + bv[i];

        if constexpr (!FINAL) {
            if (lane < LPG) {
                uint_t w[4];
                #pragma unroll
                for (int p = 0; p < 4; ++p) {
                    float v0 = fmaxf(v[2 * p], 0.f);
                    float v1 = fmaxf(v[2 * p + 1], 0.f);
                    w[p] = (uint_t)f2bf(v0) | ((uint_t)f2bf(v1) << 16);
                }
                *reinterpret_cast<uint4*>(H + (size_t)node * F + colbase) =
                    make_uint4(w[0], w[1], w[2], w[3]);
            }
        } else {
            // log_softmax over the 64 cols (8 lanes x 8 cols)
            float m = v[0];
            #pragma unroll
            for (int i = 1; i < 8; ++i) m = fmaxf(m, v[i]);
            #pragma unroll
            for (int off = 1; off < LPG; off <<= 1) m = fmaxf(m, __shfl_xor(m, off));
            float s = 0.f;
            #pragma unroll
            for (int i = 0; i < 8; ++i) s += expf(v[i] - m);
            #pragma unroll
            for (int off = 1; off < LPG; off <<= 1) s += __shfl_xor(s, off);
            float ls = m + logf(s);
            if (lane < LPG) {
                float* ho = hout + (size_t)node * 64 + colbase;
                float* lo = lout + (size_t)node * 64 + colbase;
                *reinterpret_cast<float4*>(ho) = make_float4(v[0], v[1], v[2], v[3]);
                *reinterpret_cast<float4*>(ho + 4) = make_float4(v[4], v[5], v[6], v[7]);
                *reinterpret_cast<float4*>(lo) =
                    make_float4(v[0] - ls, v[1] - ls, v[2] - ls, v[3] - ls);
                *reinterpret_cast<float4*>(lo + 4) =
                    make_float4(v[4] - ls, v[5] - ls, v[6] - ls, v[7] - ls);
            }
        }
    }
}

extern "C" void kernel_launch(void* const* d_in, const int* in_sizes, int n_in,
                              void* d_out, int out_size, void* d_ws, size_t ws_size,
                              hipStream_t stream) {
    const float* x   = (const float*)d_in[0];
    const int*   ei  = (const int*)d_in[1];
    const float* W1l = (const float*)d_in[2];
    const float* b1  = (const float*)d_in[3];
    const float* W1r = (const float*)d_in[4];
    const float* W2l = (const float*)d_in[5];
    const float* b2  = (const float*)d_in[6];
    const float* W2r = (const float*)d_in[7];
    const float* W3l = (const float*)d_in[8];
    const float* b3  = (const float*)d_in[9];
    const float* W3r = (const float*)d_in[10];
    const int* esrc = ei;
    const int* edst = ei + N_EDGES;

    char* ws = (char*)d_ws;
    size_t off = 0;
    auto alloc = [&](size_t b) { void* p = ws + off; off = (off + b + 255) & ~(size_t)255; return p; };
    unsigned char* P1 = (unsigned char*)alloc((size_t)MP * 256);  // fp8; reused as P2/P3
    ushort_t* R1 = (ushort_t*)alloc((size_t)MP * 256 * 2);        // bf16; reused as R2/R3
    ushort_t* H1 = (ushort_t*)alloc((size_t)MP * 256 * 2);
    ushort_t* H2 = (ushort_t*)alloc((size_t)MP * 128 * 2);
    int* offs = (int*)alloc((N_NODES + 1) * 4);
    int* cur  = (int*)alloc(N_NODES * 4);
    int* dcnt = (int*)alloc(N_NODES * 4);
    ushort_t* csrc = (ushort_t*)alloc(N_EDGES * 2);
    int* bsum = (int*)alloc(256 * 4);
    ushort_t* pB1 = (ushort_t*)alloc(256 * 512 * 2);
    ushort_t* pB2 = (ushort_t*)alloc(256 * 256 * 2);
    ushort_t* pB3 = (ushort_t*)alloc(128 * 128 * 2);

    unsigned char* P2 = P1;
    ushort_t* R2 = R1;
    unsigned char* P3 = P1;
    ushort_t* R3 = R1;

    int nScanBlocks = (N_NODES + 255) / 256;  // 196

    // CSR build (reused by all 3 layers)
    hipMemsetAsync(dcnt, 0, N_NODES * 4, stream);
    deg_k<<<(N_EDGES + 255) / 256, 256, 0, stream>>>(edst, dcnt, N_EDGES);
    scan1_k<<<nScanBlocks, 256, 0, stream>>>(dcnt, offs, bsum, N_NODES);
    scan2_k<<<1, 256, 0, stream>>>(bsum, nScanBlocks);
    scan3_k<<<nScanBlocks, 256, 0, stream>>>(offs, bsum, cur, N_NODES, N_EDGES);
    scat_k<<<(N_EDGES + 255) / 256, 256, 0, stream>>>(esrc, edst, cur, csrc, N_EDGES);

    // pack all weight pairs [Wl|Wr]
    pack_all_k<<<(26624 + 255) / 256, 256, 0, stream>>>(
        W1l, W1r, W2l, W2r, W3l, W3r, pB1, pB2, pB3);

    int gemmGrid = MP / 32;                    // 1564 blocks (32 rows each)
    int aggGrid = ((N_NODES + 1) / 2 + 3) / 4; // 6250 blocks (2 nodes/wave, 4 waves)
    float* hout = (float*)d_out;
    float* lout = hout + (size_t)N_NODES * 64;

    // layer 1: P1(fp8)|R1(bf16) = x(f32) @ [W1l|W1r]; h1 = relu(mean(P1)+R1+b1)
    gemm_k<256, 512, 256, true><<<gemmGrid, 256, 0, stream>>>(x, pB1, P1, R1, N_NODES);
    aggP8_k<256, false><<<aggGrid, 256, 0, stream>>>(
        P1, offs, csrc, R1, b1, H1, nullptr, nullptr, N_NODES);
    // layer 2
    gemm_k<256, 256, 128, false><<<gemmGrid, 256, 0, stream>>>(H1, pB2, P2, R2, N_NODES);
    aggP8_k<128, false><<<aggGrid, 256, 0, stream>>>(
        P2, offs, csrc, R2, b2, H2, nullptr, nullptr, N_NODES);
    // layer 3: P3(fp8)|R3(bf16) = H2 @ [W3l|W3r]; fused mean+bias+log_softmax
    gemm_k<128, 128, 64, false><<<gemmGrid, 256, 0, stream>>>(H2, pB3, P3, R3, N_NODES);
    aggP8_k<64, true><<<aggGrid, 256, 0, stream>>>(
        P3, offs, csrc, R3, b3, nullptr, hout, lout, N_NODES);
}

// Round 10
// 245.725 us; speedup vs baseline: 2.1758x; 1.0624x over previous
//
#include <hip/hip_runtime.h>
#include <hip/hip_bf16.h>

#define N_NODES 50000
#define N_EDGES 800000
#define MP 50048  // N_NODES padded to multiple of 64

typedef unsigned short ushort_t;
typedef unsigned int uint_t;
typedef __attribute__((ext_vector_type(8))) __bf16 bf16x8;
typedef __attribute__((ext_vector_type(4))) float f32x4;
typedef __attribute__((ext_vector_type(2))) float f32x2;

__device__ __forceinline__ float bf2f(uint_t u) {
    union { uint_t i; float f; } v; v.i = u << 16; return v.f;
}
__device__ __forceinline__ ushort_t f2bf(float f) {
    union { float f; uint_t i; } v; v.f = f;
    uint_t u = v.i;
    return (ushort_t)((u + 0x7FFFu + ((u >> 16) & 1u)) >> 16);
}
// accumulate 8 fp8 (e4m3) values held in a uint2
__device__ __forceinline__ void accf8(float* a, uint2 d) {
    f32x2 p;
    p = __builtin_amdgcn_cvt_pk_f32_fp8(d.x, false); a[0] += p.x; a[1] += p.y;
    p = __builtin_amdgcn_cvt_pk_f32_fp8(d.x, true);  a[2] += p.x; a[3] += p.y;
    p = __builtin_amdgcn_cvt_pk_f32_fp8(d.y, false); a[4] += p.x; a[5] += p.y;
    p = __builtin_amdgcn_cvt_pk_f32_fp8(d.y, true);  a[6] += p.x; a[7] += p.y;
}
// pack high halves of two f32 -> two bf16 (truncation)
__device__ __forceinline__ uint_t pk_hi(float a, float b) {
    return __builtin_amdgcn_perm(__float_as_uint(b), __float_as_uint(a), 0x07060302);
}

// ---------------- CSR build ----------------
__global__ void deg_k(const int* __restrict__ dst, int* __restrict__ deg, int E) {
    int e = blockIdx.x * 256 + threadIdx.x;
    if (e < E) atomicAdd(&deg[dst[e]], 1);
}

__global__ void scan1_k(const int* __restrict__ deg, int* __restrict__ offs,
                        int* __restrict__ bsum, int n) {
    __shared__ int s[256];
    int i = blockIdx.x * 256 + threadIdx.x;
    int v = (i < n) ? deg[i] : 0;
    s[threadIdx.x] = v;
    __syncthreads();
    #pragma unroll
    for (int d = 1; d < 256; d <<= 1) {
        int t = (threadIdx.x >= d) ? s[threadIdx.x - d] : 0;
        __syncthreads();
        s[threadIdx.x] += t;
        __syncthreads();
    }
    if (i < n) offs[i] = s[threadIdx.x] - v;   // exclusive
    if (threadIdx.x == 255) bsum[blockIdx.x] = s[255];
}

__global__ void scan2_k(int* __restrict__ bsum, int nb) {  // single block
    __shared__ int s[256];
    int v = (threadIdx.x < nb) ? bsum[threadIdx.x] : 0;
    s[threadIdx.x] = v;
    __syncthreads();
    #pragma unroll
    for (int d = 1; d < 256; d <<= 1) {
        int t = (threadIdx.x >= d) ? s[threadIdx.x - d] : 0;
        __syncthreads();
        s[threadIdx.x] += t;
        __syncthreads();
    }
    if (threadIdx.x < nb) bsum[threadIdx.x] = s[threadIdx.x] - v;  // exclusive
}

__global__ void scan3_k(int* __restrict__ offs, const int* __restrict__ bsum,
                        int* __restrict__ cur, int n, int E) {
    int i = blockIdx.x * 256 + threadIdx.x;
    if (i < n) {
        int v = offs[i] + bsum[blockIdx.x];
        offs[i] = v;
        cur[i] = v;
    }
    if (i == 0) offs[n] = E;
}

__global__ void scat_k(const int* __restrict__ src, const int* __restrict__ dst,
                       int* __restrict__ cur, ushort_t* __restrict__ csrc, int E) {
    int e = blockIdx.x * 256 + threadIdx.x;
    if (e < E) {
        int p = atomicAdd(&cur[dst[e]], 1);
        csrc[p] = (ushort_t)src[e];
    }
}

// ---------------- fused weight packing (all 3 layers) into MFMA frag order ----------------
// frag (kt, ct): value(lane, j) = W[kt*32 + (lane>>4)*8 + j][ct*16 + (lane&15)]
__device__ __forceinline__ void pack_one(const float* Wl, const float* Wr,
                                         ushort_t* P, int K, int F, int t) {
    int NOUT = 2 * F;
    int lane = t & 63;
    int frag = t >> 6;
    int nct = NOUT / 16;
    int ct = frag % nct;
    int kt = frag / nct;
    int col = ct * 16 + (lane & 15);
    const float* W = (col < F) ? Wl : Wr;
    int c = (col < F) ? col : col - F;
    int k0 = kt * 32 + (lane >> 4) * 8;
    uint_t w[4];
    #pragma unroll
    for (int p = 0; p < 4; ++p) {
        ushort_t lo = f2bf(W[(size_t)(k0 + 2 * p) * F + c]);
        ushort_t hi = f2bf(W[(size_t)(k0 + 2 * p + 1) * F + c]);
        w[p] = (uint_t)lo | ((uint_t)hi << 16);
    }
    *(reinterpret_cast<uint4*>(P) + t) = make_uint4(w[0], w[1], w[2], w[3]);
}

__global__ void pack_all_k(const float* __restrict__ W1l, const float* __restrict__ W1r,
                           const float* __restrict__ W2l, const float* __restrict__ W2r,
                           const float* __restrict__ W3l, const float* __restrict__ W3r,
                           ushort_t* __restrict__ pB1, ushort_t* __restrict__ pB2,
                           ushort_t* __restrict__ pB3) {
    int tid = blockIdx.x * 256 + threadIdx.x;
    if (tid < 16384)       pack_one(W1l, W1r, pB1, 256, 256, tid);
    else if (tid < 24576)  pack_one(W2l, W2r, pB2, 256, 128, tid - 16384);
    else if (tid < 26624)  pack_one(W3l, W3r, pB3, 128, 64, tid - 24576);
}

// ---------------- GEMM: B-slice in VGPRs, persistent blocks over row tiles ----------------
// Each block owns NCB output cols; each wave NCB/4 cols. The wave's whole B slice
// (KT x CTW frags) is loaded into registers ONCE, then the block grid-strides over
// 32-row tiles: stage A tile to LDS, inner loop = ds_read + MFMA only (no global).
// Weight frag as MFMA A-operand -> thread holds 4 consecutive output cols of a row.
// cols < PF -> fp8 e4m3 u32 store; cols >= PF -> bf16 uint2 store.
// F32A: stage f32 activations with fused truncate-pack to bf16 (rows clamped).
template <int K, int NOUT, int NCB, int PF, bool F32A, int BPG>
__global__ __launch_bounds__(256, 2) void gemm_k(
    const void* __restrict__ Av, const ushort_t* __restrict__ Bp,
    unsigned char* __restrict__ Pout, ushort_t* __restrict__ Rout, int nvalid) {
    constexpr int KT = K / 32;
    constexpr int CTW = NCB / 64;     // col-tiles per wave
    constexpr int NCG = NOUT / NCB;   // col groups (separate blocks)
    constexpr int RS = NOUT - PF;     // R row stride
    constexpr int PADE = K + 8;
    constexpr int NTILES = MP / 32;   // 1564
    __shared__ ushort_t Atile[32 * PADE];

    int cg = (NCG > 1) ? ((int)blockIdx.x % NCG) : 0;
    int bid = (NCG > 1) ? ((int)blockIdx.x / NCG) : (int)blockIdx.x;
    int wave = threadIdx.x >> 6;
    int lane = threadIdx.x & 63;
    int ct0 = cg * (NCB / 16) + wave * CTW;   // global col-tile base for this wave

    // ---- load this wave's whole B slice into registers (once) ----
    bf16x8 breg[KT][CTW];
    #pragma unroll
    for (int kt = 0; kt < KT; ++kt)
        #pragma unroll
        for (int ct = 0; ct < CTW; ++ct)
            breg[kt][ct] = *reinterpret_cast<const bf16x8*>(
                Bp + ((size_t)(kt * (NOUT / 16) + ct0 + ct) * 64 + lane) * 8);

    int arowoff = lane & 15;
    int r0 = (lane >> 4) * 4;
    int srow = threadIdx.x >> 3;
    int sel = (threadIdx.x & 7) * (K / 8);
    constexpr int NWR = K / 64;       // 16B chunks per thread in staging

    for (int t = bid; t < NTILES; t += BPG) {
        int rowBase = t * 32;
        __syncthreads();   // previous tile's LDS reads done
        {   // ---- stage A tile: 8 threads/row, K/8 elems each ----
            int grow = min(rowBase + srow, nvalid - 1);
            ushort_t* dst = &Atile[srow * PADE + sel];
            if (F32A) {
                const float* A = (const float*)Av + (size_t)grow * K + sel;
                #pragma unroll
                for (int i = 0; i < NWR; ++i) {
                    float4 f0 = *reinterpret_cast<const float4*>(A + i * 8);
                    float4 f1 = *reinterpret_cast<const float4*>(A + i * 8 + 4);
                    uint4 w;
                    w.x = pk_hi(f0.x, f0.y);
                    w.y = pk_hi(f0.z, f0.w);
                    w.z = pk_hi(f1.x, f1.y);
                    w.w = pk_hi(f1.z, f1.w);
                    *reinterpret_cast<uint4*>(dst + i * 8) = w;
                }
            } else {
                const ushort_t* A = (const ushort_t*)Av + (size_t)grow * K + sel;
                #pragma unroll
                for (int i = 0; i < NWR; ++i)
                    *reinterpret_cast<uint4*>(dst + i * 8) =
                        *reinterpret_cast<const uint4*>(A + i * 8);
            }
        }
        __syncthreads();

        f32x4 acc[2][CTW];
        #pragma unroll
        for (int r = 0; r < 2; ++r)
            #pragma unroll
            for (int c = 0; c < CTW; ++c) acc[r][c] = (f32x4){0.f, 0.f, 0.f, 0.f};

        const ushort_t* A0 = &Atile[arowoff * PADE + (lane >> 4) * 8];
        #pragma unroll
        for (int kt = 0; kt < KT; ++kt) {
            bf16x8 x0 = *reinterpret_cast<const bf16x8*>(A0 + kt * 32);
            bf16x8 x1 = *reinterpret_cast<const bf16x8*>(A0 + 16 * PADE + kt * 32);
            #pragma unroll
            for (int ct = 0; ct < CTW; ++ct) {
                acc[0][ct] = __builtin_amdgcn_mfma_f32_16x16x32_bf16(breg[kt][ct], x0, acc[0][ct], 0, 0, 0);
                acc[1][ct] = __builtin_amdgcn_mfma_f32_16x16x32_bf16(breg[kt][ct], x1, acc[1][ct], 0, 0, 0);
            }
        }

        #pragma unroll
        for (int r = 0; r < 2; ++r) {
            int xrow = rowBase + r * 16 + arowoff;
            #pragma unroll
            for (int ct = 0; ct < CTW; ++ct) {
                int wc = (ct0 + ct) * 16 + r0;
                f32x4 v = acc[r][ct];
                if (PF > 0 && wc < PF) {
                    uint_t u = __builtin_amdgcn_cvt_pk_fp8_f32(v[0], v[1], 0u, false);
                    u = __builtin_amdgcn_cvt_pk_fp8_f32(v[2], v[3], u, true);
                    *reinterpret_cast<uint_t*>(Pout + (size_t)xrow * PF + wc) = u;
                } else {
                    uint2 w;
                    w.x = (uint_t)f2bf(v[0]) | ((uint_t)f2bf(v[1]) << 16);
                    w.y = (uint_t)f2bf(v[2]) | ((uint_t)f2bf(v[3]) << 16);
                    *reinterpret_cast<uint2*>(Rout + (size_t)xrow * RS + (wc - PF)) = w;
                }
            }
        }
    }
}

// ---------------- fused aggregate (fp8 P) + epilogue, 2 nodes/wave ----------------
// !FINAL: H = relu(mean(P) + R + bias) bf16.
// FINAL (F=64): h = mean(P) + R + bias -> hout f32; fused log_softmax -> lout.
template <int F, bool FINAL>
__global__ __launch_bounds__(256) void aggP8_k(
    const unsigned char* __restrict__ P, const int* __restrict__ offs,
    const ushort_t* __restrict__ csrc, const ushort_t* __restrict__ R,
    const float* __restrict__ bias, ushort_t* __restrict__ H,
    float* __restrict__ hout, float* __restrict__ lout, int n) {
    constexpr int LPG = F / 8;            // 32, 16, 8 lanes cover a row (8B each)
    constexpr int G = 64 / LPG;           // 2, 4, 8 edge groups
    constexpr int U = (G >= 4) ? 1 : (4 / G);
    constexpr int ST = G * U;             // edges consumed per iter per node
    int wid = (blockIdx.x * 256 + threadIdx.x) >> 6;
    int lane = threadIdx.x & 63;
    int g = lane / LPG;
    int sub = lane & (LPG - 1);
    int colbase = sub * 8;
    int n0 = 2 * wid, n1 = 2 * wid + 1;
    if (n0 >= n) return;
    bool has1 = (n1 < n);
    int b0 = offs[n0], end0 = offs[n0 + 1];
    int b1 = has1 ? offs[n1] : 0, end1 = has1 ? offs[n1 + 1] : 0;

    float a0[8] = {0,0,0,0,0,0,0,0};
    float a1[8] = {0,0,0,0,0,0,0,0};
    int e0 = b0, e1 = b1;
    const unsigned char* Pc = P + colbase;

    while (e0 + ST <= end0 && e1 + ST <= end1) {
        uint2 d0[U], d1[U];
        #pragma unroll
        for (int u = 0; u < U; ++u) {
            int s = csrc[e0 + g + u * G];
            d0[u] = *reinterpret_cast<const uint2*>(Pc + (size_t)s * F);
        }
        #pragma unroll
        for (int u = 0; u < U; ++u) {
            int s = csrc[e1 + g + u * G];
            d1[u] = *reinterpret_cast<const uint2*>(Pc + (size_t)s * F);
        }
        #pragma unroll
        for (int u = 0; u < U; ++u) { accf8(a0, d0[u]); accf8(a1, d1[u]); }
        e0 += ST; e1 += ST;
    }
    while (e0 + ST <= end0) {
        uint2 d[U];
        #pragma unroll
        for (int u = 0; u < U; ++u) {
            int s = csrc[e0 + g + u * G];
            d[u] = *reinterpret_cast<const uint2*>(Pc + (size_t)s * F);
        }
        #pragma unroll
        for (int u = 0; u < U; ++u) accf8(a0, d[u]);
        e0 += ST;
    }
    for (int e = e0 + g; e < end0; e += G) {
        int s = csrc[e];
        uint2 d = *reinterpret_cast<const uint2*>(Pc + (size_t)s * F);
        accf8(a0, d);
    }
    while (e1 + ST <= end1) {
        uint2 d[U];
        #pragma unroll
        for (int u = 0; u < U; ++u) {
            int s = csrc[e1 + g + u * G];
            d[u] = *reinterpret_cast<const uint2*>(Pc + (size_t)s * F);
        }
        #pragma unroll
        for (int u = 0; u < U; ++u) accf8(a1, d[u]);
        e1 += ST;
    }
    for (int e = e1 + g; e < end1; e += G) {
        int s = csrc[e];
        uint2 d = *reinterpret_cast<const uint2*>(Pc + (size_t)s * F);
        accf8(a1, d);
    }

    // combine the G edge-groups: afterwards ALL lanes hold node totals
    #pragma unroll
    for (int off = LPG; off < 64; off <<= 1) {
        #pragma unroll
        for (int i = 0; i < 8; ++i) {
            a0[i] += __shfl_xor(a0[i], off);
            a1[i] += __shfl_xor(a1[i], off);
        }
    }

    float inv0 = 1.f / fmaxf((float)(end0 - b0), 1.f);
    float inv1 = 1.f / fmaxf((float)(end1 - b1), 1.f);

    #pragma unroll
    for (int j = 0; j < 2; ++j) {
        if (j && !has1) break;
        int node = j ? n1 : n0;
        float* a = j ? a1 : a0;
        float inv = j ? inv1 : inv0;
        uint4 rr = *reinterpret_cast<const uint4*>(R + (size_t)node * F + colbase);
        float r[8];
        r[0] = bf2f(rr.x & 0xffff); r[1] = bf2f(rr.x >> 16);
        r[2] = bf2f(rr.y & 0xffff); r[3] = bf2f(rr.y >> 16);
        r[4] = bf2f(rr.z & 0xffff); r[5] = bf2f(rr.z >> 16);
        r[6] = bf2f(rr.w & 0xffff); r[7] = bf2f(rr.w >> 16);
        float4 bA = *reinterpret_cast<const float4*>(bias + colbase);
        float4 bB = *reinterpret_cast<const float4*>(bias + colbase + 4);
        float bv[8] = {bA.x, bA.y, bA.z, bA.w, bB.x, bB.y, bB.z, bB.w};
        float v[8];
        #pragma unroll
        for (int i = 0; i < 8; ++i) v[i] = a[i] * inv + r[i] + bv[i];

        if constexpr (!FINAL) {
            if (lane < LPG) {
                uint_t w[4];
                #pragma unroll
                for (int p = 0; p < 4; ++p) {
                    float v0 = fmaxf(v[2 * p], 0.f);
                    float v1 = fmaxf(v[2 * p + 1], 0.f);
                    w[p] = (uint_t)f2bf(v0) | ((uint_t)f2bf(v1) << 16);
                }
                *reinterpret_cast<uint4*>(H + (size_t)node * F + colbase) =
                    make_uint4(w[0], w[1], w[2], w[3]);
            }
        } else {
            // log_softmax over the 64 cols (8 lanes x 8 cols)
            float m = v[0];
            #pragma unroll
            for (int i = 1; i < 8; ++i) m = fmaxf(m, v[i]);
            #pragma unroll
            for (int off = 1; off < LPG; off <<= 1) m = fmaxf(m, __shfl_xor(m, off));
            float s = 0.f;
            #pragma unroll
            for (int i = 0; i < 8; ++i) s += expf(v[i] - m);
            #pragma unroll
            for (int off = 1; off < LPG; off <<= 1) s += __shfl_xor(s, off);
            float ls = m + logf(s);
            if (lane < LPG) {
                float* ho = hout + (size_t)node * 64 + colbase;
                float* lo = lout + (size_t)node * 64 + colbase;
                *reinterpret_cast<float4*>(ho) = make_float4(v[0], v[1], v[2], v[3]);
                *reinterpret_cast<float4*>(ho + 4) = make_float4(v[4], v[5], v[6], v[7]);
                *reinterpret_cast<float4*>(lo) =
                    make_float4(v[0] - ls, v[1] - ls, v[2] - ls, v[3] - ls);
                *reinterpret_cast<float4*>(lo + 4) =
                    make_float4(v[4] - ls, v[5] - ls, v[6] - ls, v[7] - ls);
            }
        }
    }
}

extern "C" void kernel_launch(void* const* d_in, const int* in_sizes, int n_in,
                              void* d_out, int out_size, void* d_ws, size_t ws_size,
                              hipStream_t stream) {
    const float* x   = (const float*)d_in[0];
    const int*   ei  = (const int*)d_in[1];
    const float* W1l = (const float*)d_in[2];
    const float* b1  = (const float*)d_in[3];
    const float* W1r = (const float*)d_in[4];
    const float* W2l = (const float*)d_in[5];
    const float* b2  = (const float*)d_in[6];
    const float* W2r = (const float*)d_in[7];
    const float* W3l = (const float*)d_in[8];
    const float* b3  = (const float*)d_in[9];
    const float* W3r = (const float*)d_in[10];
    const int* esrc = ei;
    const int* edst = ei + N_EDGES;

    char* ws = (char*)d_ws;
    size_t off = 0;
    auto alloc = [&](size_t b) { void* p = ws + off; off = (off + b + 255) & ~(size_t)255; return p; };
    unsigned char* P1 = (unsigned char*)alloc((size_t)MP * 256);  // fp8; reused as P2/P3
    ushort_t* R1 = (ushort_t*)alloc((size_t)MP * 256 * 2);        // bf16; reused as R2/R3
    ushort_t* H1 = (ushort_t*)alloc((size_t)MP * 256 * 2);
    ushort_t* H2 = (ushort_t*)alloc((size_t)MP * 128 * 2);
    int* offs = (int*)alloc((N_NODES + 1) * 4);
    int* cur  = (int*)alloc(N_NODES * 4);
    int* dcnt = (int*)alloc(N_NODES * 4);
    ushort_t* csrc = (ushort_t*)alloc(N_EDGES * 2);
    int* bsum = (int*)alloc(256 * 4);
    ushort_t* pB1 = (ushort_t*)alloc(256 * 512 * 2);
    ushort_t* pB2 = (ushort_t*)alloc(256 * 256 * 2);
    ushort_t* pB3 = (ushort_t*)alloc(128 * 128 * 2);

    unsigned char* P2 = P1;
    ushort_t* R2 = R1;
    unsigned char* P3 = P1;
    ushort_t* R3 = R1;

    int nScanBlocks = (N_NODES + 255) / 256;  // 196

    // CSR build (reused by all 3 layers)
    hipMemsetAsync(dcnt, 0, N_NODES * 4, stream);
    deg_k<<<(N_EDGES + 255) / 256, 256, 0, stream>>>(edst, dcnt, N_EDGES);
    scan1_k<<<nScanBlocks, 256, 0, stream>>>(dcnt, offs, bsum, N_NODES);
    scan2_k<<<1, 256, 0, stream>>>(bsum, nScanBlocks);
    scan3_k<<<nScanBlocks, 256, 0, stream>>>(offs, bsum, cur, N_NODES, N_EDGES);
    scat_k<<<(N_EDGES + 255) / 256, 256, 0, stream>>>(esrc, edst, cur, csrc, N_EDGES);

    // pack all weight pairs [Wl|Wr]
    pack_all_k<<<(26624 + 255) / 256, 256, 0, stream>>>(
        W1l, W1r, W2l, W2r, W3l, W3r, pB1, pB2, pB3);

    constexpr int BPG = 512;                   // blocks per col-group
    int aggGrid = ((N_NODES + 1) / 2 + 3) / 4; // 6250 blocks (2 nodes/wave, 4 waves)
    float* hout = (float*)d_out;
    float* lout = hout + (size_t)N_NODES * 64;

    // layer 1: P1(fp8)|R1(bf16) = x(f32) @ [W1l|W1r]; h1 = relu(mean(P1)+R1+b1)
    gemm_k<256, 512, 256, 256, true, BPG><<<2 * BPG, 256, 0, stream>>>(x, pB1, P1, R1, N_NODES);
    aggP8_k<256, false><<<aggGrid, 256, 0, stream>>>(
        P1, offs, csrc, R1, b1, H1, nullptr, nullptr, N_NODES);
    // layer 2
    gemm_k<256, 256, 256, 128, false, BPG><<<BPG, 256, 0, stream>>>(H1, pB2, P2, R2, N_NODES);
    aggP8_k<128, false><<<aggGrid, 256, 0, stream>>>(
        P2, offs, csrc, R2, b2, H2, nullptr, nullptr, N_NODES);
    // layer 3: P3(fp8)|R3(bf16) = H2 @ [W3l|W3r]; fused mean+bias+log_softmax
    gemm_k<128, 128, 128, 64, false, BPG><<<BPG, 256, 0, stream>>>(H2, pB3, P3, R3, N_NODES);
    aggP8_k<64, true><<<aggGrid, 256, 0, stream>>>(
        P3, offs, csrc, R3, b3, nullptr, hout, lout, N_NODES);
}